// Round 4
// baseline (420.144 us; speedup 1.0000x reference)
//
#include <hip/hip_runtime.h>

#define NHEADS 16
#define DKV 128
#define BB 2
#define SS 2048
#define DD 2048

typedef __attribute__((ext_vector_type(8))) short bf16x8;
typedef __attribute__((ext_vector_type(4))) short bf16x4;
typedef __attribute__((ext_vector_type(4))) float f32x4;
typedef __attribute__((ext_vector_type(8))) _Float16 f16x8;

// scale 1/sqrt(128) * log2(e)  (we use exp2 instead of exp)
#define QSCL 0.12752775f

__device__ __forceinline__ short f2bf(float x) {
  unsigned u = __builtin_bit_cast(unsigned, x);
  unsigned r = (u + 0x7fffu + ((u >> 16) & 1u)) >> 16;  // RTNE
  return (short)(unsigned short)r;
}
__device__ __forceinline__ float bf2f(short s) {
  unsigned u = ((unsigned)(unsigned short)s) << 16;
  return __builtin_bit_cast(float, u);
}
__device__ __forceinline__ unsigned pk2bf(float a, float b) {
#if __has_builtin(__builtin_amdgcn_cvt_pk_bf16_f32)
  typedef __attribute__((ext_vector_type(2))) __bf16 bf2_t;
  bf2_t r = __builtin_amdgcn_cvt_pk_bf16_f32(a, b);
  return __builtin_bit_cast(unsigned, r);
#else
  unsigned ua = __builtin_bit_cast(unsigned, a);
  unsigned ub = __builtin_bit_cast(unsigned, b);
  return ((ua + 0x8000u) >> 16) | ((ub + 0x8000u) & 0xffff0000u);
#endif
}
__device__ __forceinline__ unsigned pkf16(float a, float b) {
#if __has_builtin(__builtin_amdgcn_cvt_pkrtz)
  typedef __attribute__((ext_vector_type(2))) __fp16 h2_t;
  h2_t r = __builtin_amdgcn_cvt_pkrtz(a, b);
  return __builtin_bit_cast(unsigned, r);
#else
  _Float16 ha = (_Float16)a, hb = (_Float16)b;
  unsigned short ua = __builtin_bit_cast(unsigned short, ha);
  unsigned short ub = __builtin_bit_cast(unsigned short, hb);
  return (unsigned)ua | ((unsigned)ub << 16);
#endif
}
__device__ __forceinline__ float exp2fast(float x) {
#if __has_builtin(__builtin_amdgcn_exp2f)
  return __builtin_amdgcn_exp2f(x);
#else
  return exp2f(x);
#endif
}

// async global->LDS, 16B/lane; lds dst = wave-uniform base + lane*16
__device__ __forceinline__ void async16(const void* g, void* l) {
  __builtin_amdgcn_global_load_lds(
      (__attribute__((address_space(1))) void*)g,
      (__attribute__((address_space(3))) void*)l, 16, 0, 0);
}

// ============ fp32 -> bf16 convert (q_in) =================================
__global__ __launch_bounds__(256) void cvt_q(const float* __restrict__ x,
                                             short* __restrict__ y) {
  int idx = blockIdx.x * 256 + threadIdx.x;
  int g = idx * 8;
  float4 a = *(const float4*)(x + g);
  float4 b = *(const float4*)(x + g + 4);
  uint4 o = {pk2bf(a.x, a.y), pk2bf(a.z, a.w), pk2bf(b.x, b.y), pk2bf(b.z, b.w)};
  *(uint4*)(y + g) = o;
}

// ============ weight transpose: W[K][N] fp32 -> Wt[N][K] bf16 * scale =====
__global__ __launch_bounds__(256) void transpose_w(
    const float* __restrict__ W, short* __restrict__ Wt, int K, int N,
    float scale) {
  __shared__ float T[32][33];
  const int nt = blockIdx.x * 32;
  const int kt = blockIdx.y * 32;
  const int tx = threadIdx.x & 31;
  const int ty = threadIdx.x >> 5;
#pragma unroll
  for (int i = 0; i < 4; ++i)
    T[ty + i * 8][tx] = W[(size_t)(kt + ty + i * 8) * N + nt + tx];
  __syncthreads();
#pragma unroll
  for (int i = 0; i < 4; ++i)
    Wt[(size_t)(nt + ty + i * 8) * K + kt + tx] = f2bf(T[tx][ty + i * 8] * scale);
}

// ============ mask bool -> float bias =====================================
__global__ void mask_bias(const unsigned char* __restrict__ m,
                          float* __restrict__ mb) {
  int i = blockIdx.x * 256 + threadIdx.x;
  mb[i] = m[i] ? -1e30f : 0.0f;
}

// ============ MFMA GEMM with async staging ================================
template <int AMODE>
__global__ __launch_bounds__(256) void gemm_as(
    const void* __restrict__ Ap, const short* __restrict__ Bt,
    const float* __restrict__ bias, void* __restrict__ Cp,
    int M, int N, int K, int KC, int cmode, float bscale) {
  __shared__ __align__(16) short As[128 * 32];
  __shared__ __align__(16) short Bs[128 * 32];
  const int tid = threadIdx.x;
  const int bm = blockIdx.y * 128;
  const int bn = blockIdx.x * 128;
  const int kz = blockIdx.z;
  const int w = tid >> 6, lane = tid & 63;
  const int lm = lane & 15, q4 = lane >> 4;
  const int m0 = (w & 1) * 64, n0 = (w >> 1) * 64;

  f32x4 acc[4][4];
#pragma unroll
  for (int mi = 0; mi < 4; ++mi)
#pragma unroll
    for (int ni = 0; ni < 4; ++ni) acc[mi][ni] = (f32x4){0.f, 0.f, 0.f, 0.f};

  const int kbeg = kz * KC;
  const int kend = kbeg + KC;

  for (int k0 = kbeg; k0 < kend; k0 += 32) {
    __syncthreads();
    if (AMODE == 1) {
      const short* Ab = (const short*)Ap;
#pragma unroll
      for (int i = 0; i < 2; ++i) {
        int rA = (w * 2 + i) * 16 + (lane >> 2);
        int cA = (lane & 3) ^ (rA & 3);
        async16(Ab + (size_t)(bm + rA) * K + k0 + cA * 8, &As[(w * 2 + i) * 512]);
      }
    } else {
      const float* Af = (const float*)Ap;
      float4 av[4];
#pragma unroll
      for (int i = 0; i < 4; ++i) {
        int qd = tid + i * 256;
        int r = qd >> 3, cq = qd & 7;
        av[i] = *(const float4*)(Af + (size_t)(bm + r) * K + k0 + cq * 4);
      }
#pragma unroll
      for (int i = 0; i < 4; ++i) {
        int qd = tid + i * 256;
        int r = qd >> 3, cq = qd & 7;
        int ch = cq >> 1, hf = cq & 1;
        int pc = ch ^ (r & 3);
        bf16x4 t = {f2bf(av[i].x), f2bf(av[i].y), f2bf(av[i].z), f2bf(av[i].w)};
        *(bf16x4*)&As[r * 32 + pc * 8 + hf * 4] = t;
      }
    }
#pragma unroll
    for (int i = 0; i < 2; ++i) {
      int rB = (w * 2 + i) * 16 + (lane >> 2);
      int cB = (lane & 3) ^ (rB & 3);
      async16(Bt + (size_t)(bn + rB) * K + k0 + cB * 8, &Bs[(w * 2 + i) * 512]);
    }
    __syncthreads();

    bf16x8 af[4], bf[4];
#pragma unroll
    for (int mi = 0; mi < 4; ++mi)
      af[mi] = *(const bf16x8*)&As[(m0 + mi * 16 + lm) * 32 + ((q4 ^ (lm & 3)) * 8)];
#pragma unroll
    for (int ni = 0; ni < 4; ++ni)
      bf[ni] = *(const bf16x8*)&Bs[(n0 + ni * 16 + lm) * 32 + ((q4 ^ (lm & 3)) * 8)];
#pragma unroll
    for (int mi = 0; mi < 4; ++mi)
#pragma unroll
      for (int ni = 0; ni < 4; ++ni)
        acc[mi][ni] = __builtin_amdgcn_mfma_f32_16x16x32_bf16(
            af[mi], bf[ni], acc[mi][ni], 0, 0, 0);
  }

  if (cmode == 2) {
    float* Cf = (float*)Cp + (size_t)kz * M * N;
#pragma unroll
    for (int mi = 0; mi < 4; ++mi)
#pragma unroll
      for (int ni = 0; ni < 4; ++ni)
#pragma unroll
        for (int reg = 0; reg < 4; ++reg)
          Cf[(size_t)(bm + m0 + mi * 16 + q4 * 4 + reg) * N +
             (bn + n0 + ni * 16 + lm)] = acc[mi][ni][reg];
  } else {
#pragma unroll
    for (int mi = 0; mi < 4; ++mi)
#pragma unroll
      for (int ni = 0; ni < 4; ++ni)
#pragma unroll
        for (int reg = 0; reg < 4; ++reg) {
          int rowg = bm + m0 + mi * 16 + q4 * 4 + reg;
          int colg = bn + n0 + ni * 16 + lm;
          float val = acc[mi][ni][reg] + bias[colg] * bscale;
          if (cmode == 0)
            ((float*)Cp)[(size_t)rowg * N + colg] = val;
          else
            ((short*)Cp)[(size_t)rowg * N + colg] = f2bf(val);
        }
  }
}

// ============ KV reduce + bias + K-RoPE + V-transpose =====================
#define SPLITK 4
__global__ __launch_bounds__(256) void kv_reduce(
    const float* __restrict__ kpart, const float* __restrict__ vpart,
    const float* __restrict__ bk, const float* __restrict__ bv,
    short* __restrict__ kp, short* __restrict__ vtb) {
  __shared__ float Kt[32][128];
  __shared__ short Vl[128][36];
  const int tid = threadIdx.x;
  const int r0 = blockIdx.x * 32;
#pragma unroll
  for (int i = 0; i < 16; ++i) {
    int e = tid + i * 256;
    int r = e >> 7, c = e & 127;
    float sk = 0.f, sv = 0.f;
#pragma unroll
    for (int z = 0; z < SPLITK; ++z) {
      sk += kpart[((size_t)z * 4096 + r0 + r) * 128 + c];
      sv += vpart[((size_t)z * 4096 + r0 + r) * 128 + c];
    }
    Kt[r][c] = sk + bk[c];
    Vl[c][r] = f2bf(sv + bv[c]);
  }
  __syncthreads();
#pragma unroll
  for (int i = 0; i < 8; ++i) {
    int e = tid + i * 256;
    int r = e >> 6, d = e & 63;
    float x1 = Kt[r][d], x2 = Kt[r][d + 64];
    float s = (float)((r0 + r) & (SS - 1));
    float ang = s * exp2fast((float)d * (-13.287712379549449f / 64.0f));
    float sn, cs;
    __sincosf(ang, &sn, &cs);
    kp[(size_t)(r0 + r) * 128 + d] = f2bf(x1 * cs - x2 * sn);
    kp[(size_t)(r0 + r) * 128 + d + 64] = f2bf(x1 * sn + x2 * cs);
  }
  const int b = r0 >> 11;
  const int j = tid >> 1, soff = (tid & 1) * 16;
  short* dst = vtb + ((size_t)b * 128 + j) * SS + (r0 & (SS - 1)) + soff;
#pragma unroll
  for (int t = 0; t < 2; ++t) {
    bf16x8 tmp;
#pragma unroll
    for (int u = 0; u < 8; ++u) tmp[u] = Vl[j][soff + t * 8 + u];
    *(bf16x8*)(dst + t * 8) = tmp;
  }
}

// ============ RoPE on projected Q (bf16, in place) ========================
__global__ __launch_bounds__(256) void rope_q(short* __restrict__ qp) {
  int idx = blockIdx.x * 256 + threadIdx.x;
  int j8 = idx & 7;
  int h = (idx >> 3) & (NHEADS - 1);
  int s = (idx >> 7) & (SS - 1);
  int b = idx >> 18;
  short* base = qp + (((size_t)b * SS + s) * NHEADS + h) * DKV + j8 * 8;
  bf16x8 x1 = *(bf16x8*)base;
  bf16x8 x2 = *(bf16x8*)(base + 64);
  bf16x8 y1, y2;
#pragma unroll
  for (int j = 0; j < 8; ++j) {
    int d = j8 * 8 + j;
    float ang = (float)s * exp2fast((float)d * (-13.287712379549449f / 64.0f));
    float sn, cs;
    __sincosf(ang, &sn, &cs);
    float a = bf2f(x1[j]), bb2 = bf2f(x2[j]);
    y1[j] = f2bf(a * cs - bb2 * sn);
    y2[j] = f2bf(a * sn + bb2 * cs);
  }
  *(bf16x8*)base = y1;
  *(bf16x8*)(base + 64) = y2;
}

// ============ flash attention v10: 8-wave blocks for occupancy ============
// Same job split as v9 (key-split chunks + fp16 partials; longest block 32
// K-tiles). Change: 512 threads = 8 waves, each wave owns 16 q-rows (ni
// dimension dropped). LDS unchanged (Kb 16K + Vb 32K + Ps 10K = 58K) ->
// still 2 blocks/CU, but now 16 waves/CU = 4 waves/SIMD (was 2): doubles
// scheduler's latency-hiding. Per-wave: 17 MFMA/tile (was 34), ~80 VGPR.
#define PSTR 40

__global__ __launch_bounds__(512, 4) void flash_kernel(
    const short* __restrict__ q, const short* __restrict__ k,
    const short* __restrict__ vt, const float* __restrict__ mb,
    short* __restrict__ out, short* __restrict__ pO, float* __restrict__ pL) {
  __shared__ __align__(16) short Kb[2][32 * 128];   // 16 KB
  __shared__ __align__(16) short Vb[2][128 * 64];   // 32 KB
  __shared__ __align__(16) short Ps[8][16 * PSTR];  // 10 KB
  // ---- job decode: size-descending classes, hb fastest ----
  const int j = blockIdx.x;
  const int cls = j >> 5, hb = j & 31;
  int qx, c;
  if (cls < 8) {                       // 8 heavy 32-tile chunks (qx>=8, c=0)
    qx = cls + 8; c = 0;
  } else {
    int kk = (cls - 8) >> 1;
    if ((cls & 1) == 0) { qx = 15 - kk; c = 1; }   // sizes 32,28,...,4
    else                { qx = 7 - kk;  c = 0; }   // sizes 32,28,...,4
  }
  const int h = hb & 15, b = hb >> 4;
  const int kt0 = c ? 32 : 0;
  int kend = 4 * qx + 4;
  if (c == 0 && kend > 32) kend = 32;

  const int tid = threadIdx.x;
  const int w = tid >> 6, lane = tid & 63;
  const int lm = lane & 15, q4 = lane >> 4;
  const int qrow0 = qx * 128 + w * 16;

  // ---- Q fragments (pre-roped, pre-scaled): B[n=q][k=d], ks4 ----
  bf16x8 qf[4];
#pragma unroll
  for (int ks = 0; ks < 4; ++ks)
    qf[ks] = *(const bf16x8*)(q +
        ((size_t)b * SS + qrow0 + lm) * (NHEADS * DKV) + h * DKV +
        ks * 32 + q4 * 8);

  bf16x8 onesb;
#pragma unroll
  for (int jj = 0; jj < 8; ++jj) onesb[jj] = (short)0x3F80;

  f32x4 O[8], Ol;
#pragma unroll
  for (int vi = 0; vi < 8; ++vi) O[vi] = (f32x4){0.f, 0.f, 0.f, 0.f};
  Ol = (f32x4){0.f, 0.f, 0.f, 0.f};

  const size_t kbase = (size_t)b * SS;

  // ---- prologue prefetch: K tile kt0 -> Kb[0], V pair {kt0,kt0+1} -> Vb[0]
  {
    {
      int r = w * 4 + (lane >> 4);
      int cc = (lane & 15) ^ (r & 7);
      async16(k + (kbase + (size_t)kt0 * 32 + r) * DKV + cc * 8,
              &Kb[0][w * 512]);
    }
#pragma unroll
    for (int i = 0; i < 2; ++i) {
      int rV = (w * 2 + i) * 8 + (lane >> 3);
      int cV = (lane & 7) ^ (rV & 7);
      async16(vt + ((size_t)b * DKV + rV) * SS + (size_t)kt0 * 32 + cV * 8,
              &Vb[0][(w * 2 + i) * 512]);
    }
  }
  f32x4 mc0 = *(const f32x4*)(mb + kbase + (size_t)kt0 * 32 + q4 * 4);
  f32x4 mc1 = *(const f32x4*)(mb + kbase + (size_t)kt0 * 32 + 16 + q4 * 4);

  for (int kt = kt0; kt < kend; ++kt) {
    __syncthreads();  // drains prefetch for tile kt (in flight since kt-1)

    f32x4 mn0, mn1;
    if (kt + 1 < kend) {
      const int t = kt + 1;
      {
        int r = w * 4 + (lane >> 4);
        int cc = (lane & 15) ^ (r & 7);
        async16(k + (kbase + (size_t)t * 32 + r) * DKV + cc * 8,
                &Kb[t & 1][w * 512]);
      }
      if (kt & 1) {  // t even: stage V pair {t, t+1}
#pragma unroll
        for (int i = 0; i < 2; ++i) {
          int rV = (w * 2 + i) * 8 + (lane >> 3);
          int cV = (lane & 7) ^ (rV & 7);
          async16(vt + ((size_t)b * DKV + rV) * SS + (size_t)t * 32 + cV * 8,
                  &Vb[(t >> 1) & 1][(w * 2 + i) * 512]);
        }
      }
      mn0 = *(const f32x4*)(mb + kbase + (size_t)t * 32 + q4 * 4);
      mn1 = *(const f32x4*)(mb + kbase + (size_t)t * 32 + 16 + q4 * 4);
    }

    // ---- S^T = K (Q*scl)^T : mi2 x ks4 ----
    const short* Kc = Kb[kt & 1];
    f32x4 sacc[2];
#pragma unroll
    for (int mi = 0; mi < 2; ++mi) sacc[mi] = (f32x4){0.f, 0.f, 0.f, 0.f};
#pragma unroll
    for (int mi = 0; mi < 2; ++mi)
#pragma unroll
      for (int ks = 0; ks < 4; ++ks) {
        bf16x8 kf = *(const bf16x8*)&Kc[(mi * 16 + lm) * 128 +
                                        (((ks * 4 + q4) ^ (lm & 7)) << 3)];
        sacc[mi] = __builtin_amdgcn_mfma_f32_16x16x32_bf16(
            kf, qf[ks], sacc[mi], 0, 0, 0);
      }

    // ---- exp2 + b64 P^T writes; causal only on last 4 tiles ----
    const bool diag = (kt >= 4 * qx);
#pragma unroll
    for (int mi = 0; mi < 2; ++mi) {
      f32x4 mbv = mi ? mc1 : mc0;
      float pv[4];
#pragma unroll
      for (int reg = 0; reg < 4; ++reg) {
        float s = sacc[mi][reg] + mbv[reg];
        if (diag) {
          int kg = kt * 32 + mi * 16 + q4 * 4 + reg;
          int qg = qrow0 + lm;
          if (kg > qg) s = -1e30f;
        }
        pv[reg] = exp2fast(s);
      }
      uint2 pkd = {pk2bf(pv[0], pv[1]), pk2bf(pv[2], pv[3])};
      *(uint2*)&Ps[w][lm * PSTR + mi * 16 + q4 * 4] = pkd;
    }
    mc0 = mn0;
    mc1 = mn1;

    // ---- O += P V ; Ol += P 1  (32 keys = one K=32 step) ----
    const short* Vc = Vb[(kt >> 1) & 1];
    const int hf4 = (kt & 1) * 4;
    bf16x8 pf = *(const bf16x8*)&Ps[w][lm * PSTR + q4 * 8];
    Ol = __builtin_amdgcn_mfma_f32_16x16x32_bf16(pf, onesb, Ol, 0, 0, 0);
#pragma unroll
    for (int vi = 0; vi < 8; ++vi) {
      bf16x8 vf = *(const bf16x8*)&Vc[(vi * 16 + lm) * 64 +
                                      (((hf4 + q4) ^ (lm & 7)) << 3)];
      O[vi] = __builtin_amdgcn_mfma_f32_16x16x32_bf16(pf, vf, O[vi], 0, 0, 0);
    }
  }

  // ---- epilogue: scale by 1/l in regs, LDS transpose, uint4 stores ----
  __syncthreads();  // all waves done with Vb; reuse as scratch
  float* Wr = (float*)&Vb[0][0] + w * 544;  // 16 rows x 34 f32 per wave
  float linv[4];
#pragma unroll
  for (int reg = 0; reg < 4; ++reg) linv[reg] = 1.0f / Ol[reg];

  const bool split = (qx >= 8);
  short* obase;
  int ostr;
  if (split) {
    int slot = ((b * 16 + h) * 8 + (qx - 8)) * 2 + c;
    obase = pO + (size_t)slot * (128 * 128);
    ostr = 128;
    // l for this chunk: lane holds Ol[reg] = l(row w*16 + q4*4 + reg),
    // identical across lm -> lanes with lm==0 write.
    if (lm == 0) {
      float* dl = pL + (size_t)slot * 128 + w * 16;
#pragma unroll
      for (int reg = 0; reg < 4; ++reg)
        dl[q4 * 4 + reg] = Ol[reg];
    }
  } else {
    obase = out + ((size_t)b * SS + qx * 128) * (NHEADS * DKV) + h * DKV;
    ostr = NHEADS * DKV;
  }

#pragma unroll
  for (int qd = 0; qd < 4; ++qd) {  // d-quarter = 32 dims (vi pair)
#pragma unroll
    for (int v2 = 0; v2 < 2; ++v2) {
      int vi = qd * 2 + v2;
#pragma unroll
      for (int reg = 0; reg < 4; ++reg)
        Wr[(q4 * 4 + reg) * 34 + v2 * 16 + lm] = O[vi][reg] * linv[reg];
    }
    // read back: lane -> row r=lane&15, col-block hh = lane>>4 (8 f32 each)
    int r = lane & 15, hh = lane >> 4;
    f32x4 t0 = *(const f32x4*)&Wr[r * 34 + hh * 8];
    f32x4 t1 = *(const f32x4*)&Wr[r * 34 + hh * 8 + 4];
    size_t oaddr = (size_t)(w * 16 + r) * ostr + qd * 32 + hh * 8;
    uint4 o0;
    if (split) {
      o0 = (uint4){pkf16(t0[0], t0[1]), pkf16(t0[2], t0[3]),
                   pkf16(t1[0], t1[1]), pkf16(t1[2], t1[3])};
    } else {
      o0 = (uint4){pk2bf(t0[0], t0[1]), pk2bf(t0[2], t0[3]),
                   pk2bf(t1[0], t1[1]), pk2bf(t1[2], t1[3])};
    }
    *(uint4*)(obase + oaddr) = o0;
  }
}

// ============ combine: O = (O0*l0 + O1*l1)/(l0+l1), fp16 -> bf16 ==========
__global__ __launch_bounds__(256) void combine(
    const short* __restrict__ pO, const float* __restrict__ pL,
    short* __restrict__ out) {
  const int qxi = blockIdx.x, h = blockIdx.y, b = blockIdx.z;
  const int qx = 8 + qxi;
  const int slot2 = ((b * 16 + h) * 8 + qxi) * 2;
  const _Float16* p0 = (const _Float16*)(pO + (size_t)slot2 * (128 * 128));
  const _Float16* p1 = p0 + 128 * 128;
  const float* l0 = pL + (size_t)slot2 * 128;
  const float* l1 = l0 + 128;
  const int t = threadIdx.x;
  const int row = t >> 1, half = t & 1;
  const float w0 = l0[row], w1 = l1[row];
  const float inv = 1.0f / (w0 + w1);
  const float a0 = w0 * inv, a1 = w1 * inv;
  const int off = row * 128 + half * 64;
  short* dst = out + ((size_t)(b * SS + qx * 128 + row)) * (NHEADS * DKV) +
               h * DKV + half * 64;
#pragma unroll
  for (int v = 0; v < 8; ++v) {
    f16x8 x0 = *(const f16x8*)(p0 + off + v * 8);
    f16x8 x1 = *(const f16x8*)(p1 + off + v * 8);
    float r[8];
#pragma unroll
    for (int u = 0; u < 8; ++u)
      r[u] = (float)x0[u] * a0 + (float)x1[u] * a1;
    uint4 o = {pk2bf(r[0], r[1]), pk2bf(r[2], r[3]),
               pk2bf(r[4], r[5]), pk2bf(r[6], r[7])};
    *(uint4*)(dst + v * 8) = o;
  }
}

// ================= launch =================================================
extern "C" void kernel_launch(void* const* d_in, const int* in_sizes, int n_in,
                              void* d_out, int out_size, void* d_ws, size_t ws_size,
                              hipStream_t stream) {
  const float* q_in = (const float*)d_in[0];
  const float* k_in = (const float*)d_in[1];
  const float* v_in = (const float*)d_in[2];
  const unsigned char* mask = (const unsigned char*)d_in[3];
  const float* Wq = (const float*)d_in[4];
  const float* bq = (const float*)d_in[5];
  const float* Wk = (const float*)d_in[6];
  const float* bk = (const float*)d_in[7];
  const float* Wv = (const float*)d_in[8];
  const float* bv = (const float*)d_in[9];
  const float* Wo = (const float*)d_in[10];
  const float* bo = (const float*)d_in[11];

  const int M = BB * SS;  // 4096
  short* Wqt = (short*)d_ws;                   // [2048][2048]
  short* Wot = Wqt + (size_t)DD * DD;          // [2048][2048]
  short* Wkt = Wot + (size_t)DD * DD;          // [128][2048]
  short* Wvt = Wkt + (size_t)DKV * DD;         // [128][2048]
  short* qb  = Wvt + (size_t)DKV * DD;         // [4096][2048] bf16 (input)
  short* qp  = qb + (size_t)M * DD;            // [4096][2048] bf16 (Q proj)
  short* kp  = qp + (size_t)M * DD;            // [4096][128] bf16 (roped K)
  short* vtb = kp + (size_t)M * DKV;           // [2][128][2048] bf16 (V^T)
  float* mb  = (float*)(vtb + (size_t)BB * DKV * SS);  // [2][2048]
  float* kpart = mb + (size_t)BB * SS;         // [4][4096][128]
  float* vpart = kpart + (size_t)SPLITK * M * DKV;
  float* pL = vpart + (size_t)SPLITK * M * DKV;  // [512][128] f32
  short* ap = qb;  // alias: qb dead after Q-proj; flash output reuses it
  // fp16 partials alias kpart+vpart (dead after kv_reduce): 512 slots x 32KB
  short* pO = (short*)kpart;

  cvt_q<<<M * DD / (8 * 256), 256, 0, stream>>>(q_in, qb);
  transpose_w<<<dim3(DD / 32, DD / 32), 256, 0, stream>>>(Wq, Wqt, DD, DD, QSCL);
  transpose_w<<<dim3(DKV / 32, DD / 32), 256, 0, stream>>>(Wk, Wkt, DD, DKV, 1.0f);
  transpose_w<<<dim3(DKV / 32, DD / 32), 256, 0, stream>>>(Wv, Wvt, DD, DKV, 1.0f);
  transpose_w<<<dim3(DD / 32, DD / 32), 256, 0, stream>>>(Wo, Wot, DD, DD, 1.0f);
  mask_bias<<<BB * SS / 256, 256, 0, stream>>>(mask, mb);

  gemm_as<1><<<dim3(DD / 128, M / 128, 1), 256, 0, stream>>>(
      qb, Wqt, bq, qp, M, DD, DD, DD, 1, QSCL);
  gemm_as<0><<<dim3(1, M / 128, SPLITK), 256, 0, stream>>>(
      k_in, Wkt, nullptr, kpart, M, DKV, DD, DD / SPLITK, 2, 1.0f);
  gemm_as<0><<<dim3(1, M / 128, SPLITK), 256, 0, stream>>>(
      v_in, Wvt, nullptr, vpart, M, DKV, DD, DD / SPLITK, 2, 1.0f);
  kv_reduce<<<M / 32, 256, 0, stream>>>(kpart, vpart, bk, bv, kp, vtb);
  rope_q<<<(BB * SS * NHEADS * 8) / 256, 256, 0, stream>>>(qp);

  flash_kernel<<<dim3(768), 512, 0, stream>>>(qp, kp, vtb, mb, ap, pO, pL);
  combine<<<dim3(8, NHEADS, BB), 256, 0, stream>>>(pO, pL, ap);

  gemm_as<1><<<dim3(DD / 128, M / 128, 1), 256, 0, stream>>>(
      ap, Wot, bo, d_out, M, DD, DD, DD, 0, 1.0f);
}

// Round 7
// 405.334 us; speedup vs baseline: 1.0365x; 1.0365x over previous
//
#include <hip/hip_runtime.h>

#define NHEADS 16
#define DKV 128
#define BB 2
#define SS 2048
#define DD 2048

typedef __attribute__((ext_vector_type(8))) short bf16x8;
typedef __attribute__((ext_vector_type(4))) short bf16x4;
typedef __attribute__((ext_vector_type(4))) float f32x4;
typedef __attribute__((ext_vector_type(8))) _Float16 f16x8;

// scale 1/sqrt(128) * log2(e)  (we use exp2 instead of exp)
#define QSCL 0.12752775f

__device__ __forceinline__ short f2bf(float x) {
  unsigned u = __builtin_bit_cast(unsigned, x);
  unsigned r = (u + 0x7fffu + ((u >> 16) & 1u)) >> 16;  // RTNE
  return (short)(unsigned short)r;
}
__device__ __forceinline__ float bf2f(short s) {
  unsigned u = ((unsigned)(unsigned short)s) << 16;
  return __builtin_bit_cast(float, u);
}
__device__ __forceinline__ unsigned pk2bf(float a, float b) {
#if __has_builtin(__builtin_amdgcn_cvt_pk_bf16_f32)
  typedef __attribute__((ext_vector_type(2))) __bf16 bf2_t;
  bf2_t r = __builtin_amdgcn_cvt_pk_bf16_f32(a, b);
  return __builtin_bit_cast(unsigned, r);
#else
  unsigned ua = __builtin_bit_cast(unsigned, a);
  unsigned ub = __builtin_bit_cast(unsigned, b);
  return ((ua + 0x8000u) >> 16) | ((ub + 0x8000u) & 0xffff0000u);
#endif
}
__device__ __forceinline__ unsigned pkf16(float a, float b) {
#if __has_builtin(__builtin_amdgcn_cvt_pkrtz)
  typedef __attribute__((ext_vector_type(2))) __fp16 h2_t;
  h2_t r = __builtin_amdgcn_cvt_pkrtz(a, b);
  return __builtin_bit_cast(unsigned, r);
#else
  _Float16 ha = (_Float16)a, hb = (_Float16)b;
  unsigned short ua = __builtin_bit_cast(unsigned short, ha);
  unsigned short ub = __builtin_bit_cast(unsigned short, hb);
  return (unsigned)ua | ((unsigned)ub << 16);
#endif
}
__device__ __forceinline__ float exp2fast(float x) {
#if __has_builtin(__builtin_amdgcn_exp2f)
  return __builtin_amdgcn_exp2f(x);
#else
  return exp2f(x);
#endif
}

// async global->LDS, 16B/lane; lds dst = wave-uniform base + lane*16
__device__ __forceinline__ void async16(const void* g, void* l) {
  __builtin_amdgcn_global_load_lds(
      (__attribute__((address_space(1))) void*)g,
      (__attribute__((address_space(3))) void*)l, 16, 0, 0);
}

// ============ batched weight transpose: 2x W[K][N] fp32 -> Wt[N][K] bf16 ==
__global__ __launch_bounds__(256) void transpose_w2(
    const float* __restrict__ W0, short* __restrict__ Wt0,
    const float* __restrict__ W1, short* __restrict__ Wt1,
    int K, int N, float s0, float s1) {
  __shared__ float T[32][33];
  const float* W = blockIdx.z ? W1 : W0;
  short* Wt = blockIdx.z ? Wt1 : Wt0;
  const float scale = blockIdx.z ? s1 : s0;
  const int nt = blockIdx.x * 32;
  const int kt = blockIdx.y * 32;
  const int tx = threadIdx.x & 31;
  const int ty = threadIdx.x >> 5;
#pragma unroll
  for (int i = 0; i < 4; ++i)
    T[ty + i * 8][tx] = W[(size_t)(kt + ty + i * 8) * N + nt + tx];
  __syncthreads();
#pragma unroll
  for (int i = 0; i < 4; ++i)
    Wt[(size_t)(nt + ty + i * 8) * K + kt + tx] = f2bf(T[tx][ty + i * 8] * scale);
}

// ============ MFMA GEMM with async staging ================================
template <int AMODE>
__global__ __launch_bounds__(256) void gemm_as(
    const void* __restrict__ Ap, const short* __restrict__ Bt,
    const float* __restrict__ bias, void* __restrict__ Cp,
    int M, int N, int K, int KC, int cmode, float bscale) {
  __shared__ __align__(16) short As[128 * 32];
  __shared__ __align__(16) short Bs[128 * 32];
  const int tid = threadIdx.x;
  const int bm = blockIdx.y * 128;
  const int bn = blockIdx.x * 128;
  const int kz = blockIdx.z;
  const int w = tid >> 6, lane = tid & 63;
  const int lm = lane & 15, q4 = lane >> 4;
  const int m0 = (w & 1) * 64, n0 = (w >> 1) * 64;

  f32x4 acc[4][4];
#pragma unroll
  for (int mi = 0; mi < 4; ++mi)
#pragma unroll
    for (int ni = 0; ni < 4; ++ni) acc[mi][ni] = (f32x4){0.f, 0.f, 0.f, 0.f};

  const int kbeg = kz * KC;
  const int kend = kbeg + KC;

  for (int k0 = kbeg; k0 < kend; k0 += 32) {
    __syncthreads();
    if (AMODE == 1) {
      const short* Ab = (const short*)Ap;
#pragma unroll
      for (int i = 0; i < 2; ++i) {
        int rA = (w * 2 + i) * 16 + (lane >> 2);
        int cA = (lane & 3) ^ (rA & 3);
        async16(Ab + (size_t)(bm + rA) * K + k0 + cA * 8, &As[(w * 2 + i) * 512]);
      }
    } else {
      const float* Af = (const float*)Ap;
      float4 av[4];
#pragma unroll
      for (int i = 0; i < 4; ++i) {
        int qd = tid + i * 256;
        int r = qd >> 3, cq = qd & 7;
        av[i] = *(const float4*)(Af + (size_t)(bm + r) * K + k0 + cq * 4);
      }
#pragma unroll
      for (int i = 0; i < 4; ++i) {
        int qd = tid + i * 256;
        int r = qd >> 3, cq = qd & 7;
        int ch = cq >> 1, hf = cq & 1;
        int pc = ch ^ (r & 3);
        bf16x4 t = {f2bf(av[i].x), f2bf(av[i].y), f2bf(av[i].z), f2bf(av[i].w)};
        *(bf16x4*)&As[r * 32 + pc * 8 + hf * 4] = t;
      }
    }
#pragma unroll
    for (int i = 0; i < 2; ++i) {
      int rB = (w * 2 + i) * 16 + (lane >> 2);
      int cB = (lane & 3) ^ (rB & 3);
      async16(Bt + (size_t)(bn + rB) * K + k0 + cB * 8, &Bs[(w * 2 + i) * 512]);
    }
    __syncthreads();

    bf16x8 af[4], bf[4];
#pragma unroll
    for (int mi = 0; mi < 4; ++mi)
      af[mi] = *(const bf16x8*)&As[(m0 + mi * 16 + lm) * 32 + ((q4 ^ (lm & 3)) * 8)];
#pragma unroll
    for (int ni = 0; ni < 4; ++ni)
      bf[ni] = *(const bf16x8*)&Bs[(n0 + ni * 16 + lm) * 32 + ((q4 ^ (lm & 3)) * 8)];
#pragma unroll
    for (int mi = 0; mi < 4; ++mi)
#pragma unroll
      for (int ni = 0; ni < 4; ++ni)
        acc[mi][ni] = __builtin_amdgcn_mfma_f32_16x16x32_bf16(
            af[mi], bf[ni], acc[mi][ni], 0, 0, 0);
  }

  if (cmode == 2) {
    float* Cf = (float*)Cp + (size_t)kz * M * N;
#pragma unroll
    for (int mi = 0; mi < 4; ++mi)
#pragma unroll
      for (int ni = 0; ni < 4; ++ni)
#pragma unroll
        for (int reg = 0; reg < 4; ++reg)
          Cf[(size_t)(bm + m0 + mi * 16 + q4 * 4 + reg) * N +
             (bn + n0 + ni * 16 + lm)] = acc[mi][ni][reg];
  } else {
#pragma unroll
    for (int mi = 0; mi < 4; ++mi)
#pragma unroll
      for (int ni = 0; ni < 4; ++ni)
#pragma unroll
        for (int reg = 0; reg < 4; ++reg) {
          int rowg = bm + m0 + mi * 16 + q4 * 4 + reg;
          int colg = bn + n0 + ni * 16 + lm;
          float val = acc[mi][ni][reg] + bias[colg] * bscale;
          if (cmode == 0)
            ((float*)Cp)[(size_t)rowg * N + colg] = val;
          else
            ((short*)Cp)[(size_t)rowg * N + colg] = f2bf(val);
        }
  }
}

// ============ merged K+V projection GEMM (fp32 A, split-K, fp32 partials) =
// grid (1, 32, 8): z&3 = split-K slice (KC=512), z>=4 selects V. 256 blocks
// = 1 block/CU. Body is the exact gemm_as<0>/cmode=2 structure (acc[4][4],
// full 128-column coverage -- R6's acc[4][2] variant left cols 32-63/96-127
// unwritten).
#define SPLITK 4
__global__ __launch_bounds__(256) void gemm_kv(
    const float* __restrict__ Ak, const float* __restrict__ Av,
    const short* __restrict__ Btk, const short* __restrict__ Btv,
    float* __restrict__ kpart, float* __restrict__ vpart) {
  __shared__ __align__(16) short As[128 * 32];
  __shared__ __align__(16) short Bs[128 * 32];
  const int tid = threadIdx.x;
  const int bm = blockIdx.y * 128;
  const int z = blockIdx.z;
  const int kz = z & 3;
  const float* Af = (z >= 4) ? Av : Ak;
  const short* Bt = (z >= 4) ? Btv : Btk;
  float* Cf = ((z >= 4) ? vpart : kpart) + (size_t)kz * (4096 * 128);
  const int K = DD, N = DKV;
  const int w = tid >> 6, lane = tid & 63;
  const int lm = lane & 15, q4 = lane >> 4;
  const int m0 = (w & 1) * 64, n0 = (w >> 1) * 64;

  f32x4 acc[4][4];
#pragma unroll
  for (int mi = 0; mi < 4; ++mi)
#pragma unroll
    for (int ni = 0; ni < 4; ++ni) acc[mi][ni] = (f32x4){0.f, 0.f, 0.f, 0.f};

  const int kbeg = kz * (DD / SPLITK);
  const int kend = kbeg + DD / SPLITK;

  for (int k0 = kbeg; k0 < kend; k0 += 32) {
    __syncthreads();
    {
      float4 av[4];
#pragma unroll
      for (int i = 0; i < 4; ++i) {
        int qd = tid + i * 256;
        int r = qd >> 3, cq = qd & 7;
        av[i] = *(const float4*)(Af + (size_t)(bm + r) * K + k0 + cq * 4);
      }
#pragma unroll
      for (int i = 0; i < 4; ++i) {
        int qd = tid + i * 256;
        int r = qd >> 3, cq = qd & 7;
        int ch = cq >> 1, hf = cq & 1;
        int pc = ch ^ (r & 3);
        bf16x4 t = {f2bf(av[i].x), f2bf(av[i].y), f2bf(av[i].z), f2bf(av[i].w)};
        *(bf16x4*)&As[r * 32 + pc * 8 + hf * 4] = t;
      }
    }
    // B: 128 rows (N=128); exact gemm_as pattern with bn=0.
#pragma unroll
    for (int i = 0; i < 2; ++i) {
      int rB = (w * 2 + i) * 16 + (lane >> 2);
      int cB = (lane & 3) ^ (rB & 3);
      async16(Bt + (size_t)rB * K + k0 + cB * 8, &Bs[(w * 2 + i) * 512]);
    }
    __syncthreads();

    bf16x8 af[4], bf[4];
#pragma unroll
    for (int mi = 0; mi < 4; ++mi)
      af[mi] = *(const bf16x8*)&As[(m0 + mi * 16 + lm) * 32 + ((q4 ^ (lm & 3)) * 8)];
#pragma unroll
    for (int ni = 0; ni < 4; ++ni)
      bf[ni] = *(const bf16x8*)&Bs[(n0 + ni * 16 + lm) * 32 + ((q4 ^ (lm & 3)) * 8)];
#pragma unroll
    for (int mi = 0; mi < 4; ++mi)
#pragma unroll
      for (int ni = 0; ni < 4; ++ni)
        acc[mi][ni] = __builtin_amdgcn_mfma_f32_16x16x32_bf16(
            af[mi], bf[ni], acc[mi][ni], 0, 0, 0);
  }

#pragma unroll
  for (int mi = 0; mi < 4; ++mi)
#pragma unroll
    for (int ni = 0; ni < 4; ++ni)
#pragma unroll
      for (int reg = 0; reg < 4; ++reg)
        Cf[(size_t)(bm + m0 + mi * 16 + q4 * 4 + reg) * N +
           (n0 + ni * 16 + lm)] = acc[mi][ni][reg];
}

// ============ KV reduce + bias + K-RoPE + V-transpose + mask bias =========
__global__ __launch_bounds__(256) void kv_reduce(
    const float* __restrict__ kpart, const float* __restrict__ vpart,
    const float* __restrict__ bk, const float* __restrict__ bv,
    short* __restrict__ kp, short* __restrict__ vtb,
    const unsigned char* __restrict__ m, float* __restrict__ mb) {
  __shared__ float Kt[32][128];
  __shared__ short Vl[128][36];
  const int tid = threadIdx.x;
  const int r0 = blockIdx.x * 32;
  if (tid < 32) mb[r0 + tid] = m[r0 + tid] ? -1e30f : 0.0f;
#pragma unroll
  for (int i = 0; i < 16; ++i) {
    int e = tid + i * 256;
    int r = e >> 7, c = e & 127;
    float sk = 0.f, sv = 0.f;
#pragma unroll
    for (int z = 0; z < SPLITK; ++z) {
      sk += kpart[((size_t)z * 4096 + r0 + r) * 128 + c];
      sv += vpart[((size_t)z * 4096 + r0 + r) * 128 + c];
    }
    Kt[r][c] = sk + bk[c];
    Vl[c][r] = f2bf(sv + bv[c]);
  }
  __syncthreads();
#pragma unroll
  for (int i = 0; i < 8; ++i) {
    int e = tid + i * 256;
    int r = e >> 6, d = e & 63;
    float x1 = Kt[r][d], x2 = Kt[r][d + 64];
    float s = (float)((r0 + r) & (SS - 1));
    float ang = s * exp2fast((float)d * (-13.287712379549449f / 64.0f));
    float sn, cs;
    __sincosf(ang, &sn, &cs);
    kp[(size_t)(r0 + r) * 128 + d] = f2bf(x1 * cs - x2 * sn);
    kp[(size_t)(r0 + r) * 128 + d + 64] = f2bf(x1 * sn + x2 * cs);
  }
  const int b = r0 >> 11;
  const int j = tid >> 1, soff = (tid & 1) * 16;
  short* dst = vtb + ((size_t)b * 128 + j) * SS + (r0 & (SS - 1)) + soff;
#pragma unroll
  for (int t = 0; t < 2; ++t) {
    bf16x8 tmp;
#pragma unroll
    for (int u = 0; u < 8; ++u) tmp[u] = Vl[j][soff + t * 8 + u];
    *(bf16x8*)(dst + t * 8) = tmp;
  }
}

// ============ flash attention v11: v10 + fused Q-RoPE =====================
// Same job split as v9/v10. RoPE on Q applied in-register at Q-fragment
// load: pair (d, d+64) is lane-local (qf[ks] <-> qf[ks+2], same element).
// ~16 sincos per lane once per block -- removes the 33 MB rope_q pass.
#define PSTR 40

__global__ __launch_bounds__(512, 4) void flash_kernel(
    const short* __restrict__ q, const short* __restrict__ k,
    const short* __restrict__ vt, const float* __restrict__ mb,
    short* __restrict__ out, short* __restrict__ pO, float* __restrict__ pL) {
  __shared__ __align__(16) short Kb[2][32 * 128];   // 16 KB
  __shared__ __align__(16) short Vb[2][128 * 64];   // 32 KB
  __shared__ __align__(16) short Ps[8][16 * PSTR];  // 10 KB
  // ---- job decode: size-descending classes, hb fastest ----
  const int j = blockIdx.x;
  const int cls = j >> 5, hb = j & 31;
  int qx, c;
  if (cls < 8) {                       // 8 heavy 32-tile chunks (qx>=8, c=0)
    qx = cls + 8; c = 0;
  } else {
    int kk = (cls - 8) >> 1;
    if ((cls & 1) == 0) { qx = 15 - kk; c = 1; }   // sizes 32,28,...,4
    else                { qx = 7 - kk;  c = 0; }   // sizes 32,28,...,4
  }
  const int h = hb & 15, b = hb >> 4;
  const int kt0 = c ? 32 : 0;
  int kend = 4 * qx + 4;
  if (c == 0 && kend > 32) kend = 32;

  const int tid = threadIdx.x;
  const int w = tid >> 6, lane = tid & 63;
  const int lm = lane & 15, q4 = lane >> 4;
  const int qrow0 = qx * 128 + w * 16;

  // ---- Q fragments (pre-scaled via Wqt; roped here): B[n=q][k=d], ks4 ----
  bf16x8 qf[4];
#pragma unroll
  for (int ks = 0; ks < 4; ++ks)
    qf[ks] = *(const bf16x8*)(q +
        ((size_t)b * SS + qrow0 + lm) * (NHEADS * DKV) + h * DKV +
        ks * 32 + q4 * 8);
  {
    float s = (float)(qrow0 + lm);
#pragma unroll
    for (int ks = 0; ks < 2; ++ks) {
      bf16x8 x1 = qf[ks], x2 = qf[ks + 2];
      bf16x8 y1, y2;
#pragma unroll
      for (int jj = 0; jj < 8; ++jj) {
        int d = ks * 32 + q4 * 8 + jj;
        float ang = s * exp2fast((float)d * (-13.287712379549449f / 64.0f));
        float sn, cs;
        __sincosf(ang, &sn, &cs);
        float a = bf2f(x1[jj]), b2 = bf2f(x2[jj]);
        y1[jj] = f2bf(a * cs - b2 * sn);
        y2[jj] = f2bf(a * sn + b2 * cs);
      }
      qf[ks] = y1;
      qf[ks + 2] = y2;
    }
  }

  bf16x8 onesb;
#pragma unroll
  for (int jj = 0; jj < 8; ++jj) onesb[jj] = (short)0x3F80;

  f32x4 O[8], Ol;
#pragma unroll
  for (int vi = 0; vi < 8; ++vi) O[vi] = (f32x4){0.f, 0.f, 0.f, 0.f};
  Ol = (f32x4){0.f, 0.f, 0.f, 0.f};

  const size_t kbase = (size_t)b * SS;

  // ---- prologue prefetch: K tile kt0 -> Kb[0], V pair {kt0,kt0+1} -> Vb[0]
  {
    {
      int r = w * 4 + (lane >> 4);
      int cc = (lane & 15) ^ (r & 7);
      async16(k + (kbase + (size_t)kt0 * 32 + r) * DKV + cc * 8,
              &Kb[0][w * 512]);
    }
#pragma unroll
    for (int i = 0; i < 2; ++i) {
      int rV = (w * 2 + i) * 8 + (lane >> 3);
      int cV = (lane & 7) ^ (rV & 7);
      async16(vt + ((size_t)b * DKV + rV) * SS + (size_t)kt0 * 32 + cV * 8,
              &Vb[0][(w * 2 + i) * 512]);
    }
  }
  f32x4 mc0 = *(const f32x4*)(mb + kbase + (size_t)kt0 * 32 + q4 * 4);
  f32x4 mc1 = *(const f32x4*)(mb + kbase + (size_t)kt0 * 32 + 16 + q4 * 4);

  for (int kt = kt0; kt < kend; ++kt) {
    __syncthreads();  // drains prefetch for tile kt (in flight since kt-1)

    f32x4 mn0, mn1;
    if (kt + 1 < kend) {
      const int t = kt + 1;
      {
        int r = w * 4 + (lane >> 4);
        int cc = (lane & 15) ^ (r & 7);
        async16(k + (kbase + (size_t)t * 32 + r) * DKV + cc * 8,
                &Kb[t & 1][w * 512]);
      }
      if (kt & 1) {  // t even: stage V pair {t, t+1}
#pragma unroll
        for (int i = 0; i < 2; ++i) {
          int rV = (w * 2 + i) * 8 + (lane >> 3);
          int cV = (lane & 7) ^ (rV & 7);
          async16(vt + ((size_t)b * DKV + rV) * SS + (size_t)t * 32 + cV * 8,
                  &Vb[(t >> 1) & 1][(w * 2 + i) * 512]);
        }
      }
      mn0 = *(const f32x4*)(mb + kbase + (size_t)t * 32 + q4 * 4);
      mn1 = *(const f32x4*)(mb + kbase + (size_t)t * 32 + 16 + q4 * 4);
    }

    // ---- S^T = K (Q*scl)^T : mi2 x ks4 ----
    const short* Kc = Kb[kt & 1];
    f32x4 sacc[2];
#pragma unroll
    for (int mi = 0; mi < 2; ++mi) sacc[mi] = (f32x4){0.f, 0.f, 0.f, 0.f};
#pragma unroll
    for (int mi = 0; mi < 2; ++mi)
#pragma unroll
      for (int ks = 0; ks < 4; ++ks) {
        bf16x8 kf = *(const bf16x8*)&Kc[(mi * 16 + lm) * 128 +
                                        (((ks * 4 + q4) ^ (lm & 7)) << 3)];
        sacc[mi] = __builtin_amdgcn_mfma_f32_16x16x32_bf16(
            kf, qf[ks], sacc[mi], 0, 0, 0);
      }

    // ---- exp2 + b64 P^T writes; causal only on last 4 tiles ----
    const bool diag = (kt >= 4 * qx);
#pragma unroll
    for (int mi = 0; mi < 2; ++mi) {
      f32x4 mbv = mi ? mc1 : mc0;
      float pv[4];
#pragma unroll
      for (int reg = 0; reg < 4; ++reg) {
        float s = sacc[mi][reg] + mbv[reg];
        if (diag) {
          int kg = kt * 32 + mi * 16 + q4 * 4 + reg;
          int qg = qrow0 + lm;
          if (kg > qg) s = -1e30f;
        }
        pv[reg] = exp2fast(s);
      }
      uint2 pkd = {pk2bf(pv[0], pv[1]), pk2bf(pv[2], pv[3])};
      *(uint2*)&Ps[w][lm * PSTR + mi * 16 + q4 * 4] = pkd;
    }
    mc0 = mn0;
    mc1 = mn1;

    // ---- O += P V ; Ol += P 1  (32 keys = one K=32 step) ----
    const short* Vc = Vb[(kt >> 1) & 1];
    const int hf4 = (kt & 1) * 4;
    bf16x8 pf = *(const bf16x8*)&Ps[w][lm * PSTR + q4 * 8];
    Ol = __builtin_amdgcn_mfma_f32_16x16x32_bf16(pf, onesb, Ol, 0, 0, 0);
#pragma unroll
    for (int vi = 0; vi < 8; ++vi) {
      bf16x8 vf = *(const bf16x8*)&Vc[(vi * 16 + lm) * 64 +
                                      (((hf4 + q4) ^ (lm & 7)) << 3)];
      O[vi] = __builtin_amdgcn_mfma_f32_16x16x32_bf16(pf, vf, O[vi], 0, 0, 0);
    }
  }

  // ---- epilogue: scale by 1/l in regs, LDS transpose, uint4 stores ----
  __syncthreads();  // all waves done with Vb; reuse as scratch
  float* Wr = (float*)&Vb[0][0] + w * 544;  // 16 rows x 34 f32 per wave
  float linv[4];
#pragma unroll
  for (int reg = 0; reg < 4; ++reg) linv[reg] = 1.0f / Ol[reg];

  const bool split = (qx >= 8);
  short* obase;
  int ostr;
  if (split) {
    int slot = ((b * 16 + h) * 8 + (qx - 8)) * 2 + c;
    obase = pO + (size_t)slot * (128 * 128);
    ostr = 128;
    if (lm == 0) {
      float* dl = pL + (size_t)slot * 128 + w * 16;
#pragma unroll
      for (int reg = 0; reg < 4; ++reg)
        dl[q4 * 4 + reg] = Ol[reg];
    }
  } else {
    obase = out + ((size_t)b * SS + qx * 128) * (NHEADS * DKV) + h * DKV;
    ostr = NHEADS * DKV;
  }

#pragma unroll
  for (int qd = 0; qd < 4; ++qd) {  // d-quarter = 32 dims (vi pair)
#pragma unroll
    for (int v2 = 0; v2 < 2; ++v2) {
      int vi = qd * 2 + v2;
#pragma unroll
      for (int reg = 0; reg < 4; ++reg)
        Wr[(q4 * 4 + reg) * 34 + v2 * 16 + lm] = O[vi][reg] * linv[reg];
    }
    int r = lane & 15, hh = lane >> 4;
    f32x4 t0 = *(const f32x4*)&Wr[r * 34 + hh * 8];
    f32x4 t1 = *(const f32x4*)&Wr[r * 34 + hh * 8 + 4];
    size_t oaddr = (size_t)(w * 16 + r) * ostr + qd * 32 + hh * 8;
    uint4 o0;
    if (split) {
      o0 = (uint4){pkf16(t0[0], t0[1]), pkf16(t0[2], t0[3]),
                   pkf16(t1[0], t1[1]), pkf16(t1[2], t1[3])};
    } else {
      o0 = (uint4){pk2bf(t0[0], t0[1]), pk2bf(t0[2], t0[3]),
                   pk2bf(t1[0], t1[1]), pk2bf(t1[2], t1[3])};
    }
    *(uint4*)(obase + oaddr) = o0;
  }
}

// ============ combine: O = (O0*l0 + O1*l1)/(l0+l1), fp16 -> bf16 ==========
__global__ __launch_bounds__(256) void combine(
    const short* __restrict__ pO, const float* __restrict__ pL,
    short* __restrict__ out) {
  const int qxi = blockIdx.x, h = blockIdx.y, b = blockIdx.z;
  const int qx = 8 + qxi;
  const int slot2 = ((b * 16 + h) * 8 + qxi) * 2;
  const _Float16* p0 = (const _Float16*)(pO + (size_t)slot2 * (128 * 128));
  const _Float16* p1 = p0 + 128 * 128;
  const float* l0 = pL + (size_t)slot2 * 128;
  const float* l1 = l0 + 128;
  const int t = threadIdx.x;
  const int row = t >> 1, half = t & 1;
  const float w0 = l0[row], w1 = l1[row];
  const float inv = 1.0f / (w0 + w1);
  const float a0 = w0 * inv, a1 = w1 * inv;
  const int off = row * 128 + half * 64;
  short* dst = out + ((size_t)(b * SS + qx * 128 + row)) * (NHEADS * DKV) +
               h * DKV + half * 64;
#pragma unroll
  for (int v = 0; v < 8; ++v) {
    f16x8 x0 = *(const f16x8*)(p0 + off + v * 8);
    f16x8 x1 = *(const f16x8*)(p1 + off + v * 8);
    float r[8];
#pragma unroll
    for (int u = 0; u < 8; ++u)
      r[u] = (float)x0[u] * a0 + (float)x1[u] * a1;
    uint4 o = {pk2bf(r[0], r[1]), pk2bf(r[2], r[3]),
               pk2bf(r[4], r[5]), pk2bf(r[6], r[7])};
    *(uint4*)(dst + v * 8) = o;
  }
}

// ================= launch =================================================
extern "C" void kernel_launch(void* const* d_in, const int* in_sizes, int n_in,
                              void* d_out, int out_size, void* d_ws, size_t ws_size,
                              hipStream_t stream) {
  const float* q_in = (const float*)d_in[0];
  const float* k_in = (const float*)d_in[1];
  const float* v_in = (const float*)d_in[2];
  const unsigned char* mask = (const unsigned char*)d_in[3];
  const float* Wq = (const float*)d_in[4];
  const float* bq = (const float*)d_in[5];
  const float* Wk = (const float*)d_in[6];
  const float* bk = (const float*)d_in[7];
  const float* Wv = (const float*)d_in[8];
  const float* bv = (const float*)d_in[9];
  const float* Wo = (const float*)d_in[10];
  const float* bo = (const float*)d_in[11];

  const int M = BB * SS;  // 4096
  short* Wqt = (short*)d_ws;                   // [2048][2048]
  short* Wot = Wqt + (size_t)DD * DD;          // [2048][2048]
  short* Wkt = Wot + (size_t)DD * DD;          // [128][2048]
  short* Wvt = Wkt + (size_t)DKV * DD;         // [128][2048]
  short* qb  = Wvt + (size_t)DKV * DD;         // [4096][2048] bf16 (scratch)
  short* qp  = qb + (size_t)M * DD;            // [4096][2048] bf16 (Q proj)
  short* kp  = qp + (size_t)M * DD;            // [4096][128] bf16 (roped K)
  short* vtb = kp + (size_t)M * DKV;           // [2][128][2048] bf16 (V^T)
  float* mb  = (float*)(vtb + (size_t)BB * DKV * SS);  // [2][2048]
  float* kpart = mb + (size_t)BB * SS;         // [4][4096][128]
  float* vpart = kpart + (size_t)SPLITK * M * DKV;
  float* pL = vpart + (size_t)SPLITK * M * DKV;  // [512][128] f32
  short* ap = qb;  // flash output buffer (qb otherwise unused now)
  // fp16 partials alias kpart+vpart (dead after kv_reduce): 512 slots x 32KB
  short* pO = (short*)kpart;

  transpose_w2<<<dim3(DD / 32, DD / 32, 2), 256, 0, stream>>>(
      Wq, Wqt, Wo, Wot, DD, DD, QSCL, 1.0f);
  transpose_w2<<<dim3(DKV / 32, DD / 32, 2), 256, 0, stream>>>(
      Wk, Wkt, Wv, Wvt, DD, DKV, 1.0f, 1.0f);

  gemm_kv<<<dim3(1, M / 128, 2 * SPLITK), 256, 0, stream>>>(
      k_in, v_in, Wkt, Wvt, kpart, vpart);
  gemm_as<0><<<dim3(DD / 128, M / 128, 1), 256, 0, stream>>>(
      q_in, Wqt, bq, qp, M, DD, DD, DD, 1, QSCL);
  kv_reduce<<<M / 32, 256, 0, stream>>>(kpart, vpart, bk, bv, kp, vtb, mask, mb);

  flash_kernel<<<dim3(768), 512, 0, stream>>>(qp, kp, vtb, mb, ap, pO, pL);
  combine<<<dim3(8, NHEADS, BB), 256, 0, stream>>>(pO, pL, ap);

  gemm_as<1><<<dim3(DD / 128, M / 128, 1), 256, 0, stream>>>(
      ap, Wot, bo, d_out, M, DD, DD, DD, 0, 1.0f);
}

// Round 8
// 387.700 us; speedup vs baseline: 1.0837x; 1.0455x over previous
//
#include <hip/hip_runtime.h>

#define NHEADS 16
#define DKV 128
#define BB 2
#define SS 2048
#define DD 2048

typedef __attribute__((ext_vector_type(8))) short bf16x8;
typedef __attribute__((ext_vector_type(4))) short bf16x4;
typedef __attribute__((ext_vector_type(4))) float f32x4;
typedef __attribute__((ext_vector_type(8))) _Float16 f16x8;

// scale 1/sqrt(128) * log2(e)  (we use exp2 instead of exp)
#define QSCL 0.12752775f

__device__ __forceinline__ short f2bf(float x) {
  unsigned u = __builtin_bit_cast(unsigned, x);
  unsigned r = (u + 0x7fffu + ((u >> 16) & 1u)) >> 16;  // RTNE
  return (short)(unsigned short)r;
}
__device__ __forceinline__ float bf2f(short s) {
  unsigned u = ((unsigned)(unsigned short)s) << 16;
  return __builtin_bit_cast(float, u);
}
__device__ __forceinline__ unsigned pk2bf(float a, float b) {
#if __has_builtin(__builtin_amdgcn_cvt_pk_bf16_f32)
  typedef __attribute__((ext_vector_type(2))) __bf16 bf2_t;
  bf2_t r = __builtin_amdgcn_cvt_pk_bf16_f32(a, b);
  return __builtin_bit_cast(unsigned, r);
#else
  unsigned ua = __builtin_bit_cast(unsigned, a);
  unsigned ub = __builtin_bit_cast(unsigned, b);
  return ((ua + 0x8000u) >> 16) | ((ub + 0x8000u) & 0xffff0000u);
#endif
}
__device__ __forceinline__ unsigned pkf16(float a, float b) {
#if __has_builtin(__builtin_amdgcn_cvt_pkrtz)
  typedef __attribute__((ext_vector_type(2))) __fp16 h2_t;
  h2_t r = __builtin_amdgcn_cvt_pkrtz(a, b);
  return __builtin_bit_cast(unsigned, r);
#else
  _Float16 ha = (_Float16)a, hb = (_Float16)b;
  unsigned short ua = __builtin_bit_cast(unsigned short, ha);
  unsigned short ub = __builtin_bit_cast(unsigned short, hb);
  return (unsigned)ua | ((unsigned)ub << 16);
#endif
}
__device__ __forceinline__ float exp2fast(float x) {
#if __has_builtin(__builtin_amdgcn_exp2f)
  return __builtin_amdgcn_exp2f(x);
#else
  return exp2f(x);
#endif
}

// async global->LDS, 16B/lane; lds dst = wave-uniform base + lane*16
__device__ __forceinline__ void async16(const void* g, void* l) {
  __builtin_amdgcn_global_load_lds(
      (__attribute__((address_space(1))) void*)g,
      (__attribute__((address_space(3))) void*)l, 16, 0, 0);
}

// ============ fp32 -> bf16 convert (q_in) =================================
__global__ __launch_bounds__(256) void cvt_q(const float* __restrict__ x,
                                             short* __restrict__ y) {
  int idx = blockIdx.x * 256 + threadIdx.x;
  int g = idx * 8;
  float4 a = *(const float4*)(x + g);
  float4 b = *(const float4*)(x + g + 4);
  uint4 o = {pk2bf(a.x, a.y), pk2bf(a.z, a.w), pk2bf(b.x, b.y), pk2bf(b.z, b.w)};
  *(uint4*)(y + g) = o;
}

// ============ batched weight transpose: 2x W[K][N] fp32 -> Wt[N][K] bf16 ==
__global__ __launch_bounds__(256) void transpose_w2(
    const float* __restrict__ W0, short* __restrict__ Wt0,
    const float* __restrict__ W1, short* __restrict__ Wt1,
    int K, int N, float s0, float s1) {
  __shared__ float T[32][33];
  const float* W = blockIdx.z ? W1 : W0;
  short* Wt = blockIdx.z ? Wt1 : Wt0;
  const float scale = blockIdx.z ? s1 : s0;
  const int nt = blockIdx.x * 32;
  const int kt = blockIdx.y * 32;
  const int tx = threadIdx.x & 31;
  const int ty = threadIdx.x >> 5;
#pragma unroll
  for (int i = 0; i < 4; ++i)
    T[ty + i * 8][tx] = W[(size_t)(kt + ty + i * 8) * N + nt + tx];
  __syncthreads();
#pragma unroll
  for (int i = 0; i < 4; ++i)
    Wt[(size_t)(nt + ty + i * 8) * K + kt + tx] = f2bf(T[tx][ty + i * 8] * scale);
}

// ============ MFMA GEMM with async staging ================================
// XCD-aware block remap for the 512-block (16x32) launches: default linear
// id L = x + 16y round-robins XCD = L%8 = x%8, so every XCD touches ALL 32
// A-row-panels (268 MB of A requests; measured FETCH 135 MB). Remap gives
// each XCD an 8x8 tile rectangle (4 MB A + 4 MB B, L2-sized). Bijective:
// i=L&7, t=L>>3 -> row=8*(i>>1)+(t&7), col=2*(t>>3)+(i&1).
template <int AMODE>
__global__ __launch_bounds__(256) void gemm_as(
    const void* __restrict__ Ap, const short* __restrict__ Bt,
    const float* __restrict__ bias, void* __restrict__ Cp,
    int M, int N, int K, int KC, int cmode, float bscale) {
  __shared__ __align__(16) short As[128 * 32];
  __shared__ __align__(16) short Bs[128 * 32];
  const int tid = threadIdx.x;
  int bxi = blockIdx.x, byi = blockIdx.y;
  if (gridDim.x == 16 && gridDim.y == 32) {
    int L = byi * 16 + bxi;
    int i = L & 7, t = L >> 3;
    byi = 8 * (i >> 1) + (t & 7);
    bxi = 2 * (t >> 3) + (i & 1);
  }
  const int bm = byi * 128;
  const int bn = bxi * 128;
  const int kz = blockIdx.z;
  const int w = tid >> 6, lane = tid & 63;
  const int lm = lane & 15, q4 = lane >> 4;
  const int m0 = (w & 1) * 64, n0 = (w >> 1) * 64;

  f32x4 acc[4][4];
#pragma unroll
  for (int mi = 0; mi < 4; ++mi)
#pragma unroll
    for (int ni = 0; ni < 4; ++ni) acc[mi][ni] = (f32x4){0.f, 0.f, 0.f, 0.f};

  const int kbeg = kz * KC;
  const int kend = kbeg + KC;

  for (int k0 = kbeg; k0 < kend; k0 += 32) {
    __syncthreads();
    if (AMODE == 1) {
      const short* Ab = (const short*)Ap;
#pragma unroll
      for (int i = 0; i < 2; ++i) {
        int rA = (w * 2 + i) * 16 + (lane >> 2);
        int cA = (lane & 3) ^ (rA & 3);
        async16(Ab + (size_t)(bm + rA) * K + k0 + cA * 8, &As[(w * 2 + i) * 512]);
      }
    } else {
      const float* Af = (const float*)Ap;
      float4 av[4];
#pragma unroll
      for (int i = 0; i < 4; ++i) {
        int qd = tid + i * 256;
        int r = qd >> 3, cq = qd & 7;
        av[i] = *(const float4*)(Af + (size_t)(bm + r) * K + k0 + cq * 4);
      }
#pragma unroll
      for (int i = 0; i < 4; ++i) {
        int qd = tid + i * 256;
        int r = qd >> 3, cq = qd & 7;
        int ch = cq >> 1, hf = cq & 1;
        int pc = ch ^ (r & 3);
        bf16x4 t = {f2bf(av[i].x), f2bf(av[i].y), f2bf(av[i].z), f2bf(av[i].w)};
        *(bf16x4*)&As[r * 32 + pc * 8 + hf * 4] = t;
      }
    }
#pragma unroll
    for (int i = 0; i < 2; ++i) {
      int rB = (w * 2 + i) * 16 + (lane >> 2);
      int cB = (lane & 3) ^ (rB & 3);
      async16(Bt + (size_t)(bn + rB) * K + k0 + cB * 8, &Bs[(w * 2 + i) * 512]);
    }
    __syncthreads();

    bf16x8 af[4], bf[4];
#pragma unroll
    for (int mi = 0; mi < 4; ++mi)
      af[mi] = *(const bf16x8*)&As[(m0 + mi * 16 + lm) * 32 + ((q4 ^ (lm & 3)) * 8)];
#pragma unroll
    for (int ni = 0; ni < 4; ++ni)
      bf[ni] = *(const bf16x8*)&Bs[(n0 + ni * 16 + lm) * 32 + ((q4 ^ (lm & 3)) * 8)];
#pragma unroll
    for (int mi = 0; mi < 4; ++mi)
#pragma unroll
      for (int ni = 0; ni < 4; ++ni)
        acc[mi][ni] = __builtin_amdgcn_mfma_f32_16x16x32_bf16(
            af[mi], bf[ni], acc[mi][ni], 0, 0, 0);
  }

  if (cmode == 2) {
    float* Cf = (float*)Cp + (size_t)kz * M * N;
#pragma unroll
    for (int mi = 0; mi < 4; ++mi)
#pragma unroll
      for (int ni = 0; ni < 4; ++ni)
#pragma unroll
        for (int reg = 0; reg < 4; ++reg)
          Cf[(size_t)(bm + m0 + mi * 16 + q4 * 4 + reg) * N +
             (bn + n0 + ni * 16 + lm)] = acc[mi][ni][reg];
  } else {
#pragma unroll
    for (int mi = 0; mi < 4; ++mi)
#pragma unroll
      for (int ni = 0; ni < 4; ++ni)
#pragma unroll
        for (int reg = 0; reg < 4; ++reg) {
          int rowg = bm + m0 + mi * 16 + q4 * 4 + reg;
          int colg = bn + n0 + ni * 16 + lm;
          float val = acc[mi][ni][reg] + bias[colg] * bscale;
          if (cmode == 0)
            ((float*)Cp)[(size_t)rowg * N + colg] = val;
          else
            ((short*)Cp)[(size_t)rowg * N + colg] = f2bf(val);
        }
  }
}

// ============ merged K+V projection GEMM (fp32 A, split-K, fp32 partials) =
// grid (1, 32, 8): z&3 = split-K slice (KC=512), z>=4 selects V. 256 blocks
// = 1 block/CU. Exact gemm_as<0>/cmode=2 structure (acc[4][4]).
#define SPLITK 4
__global__ __launch_bounds__(256) void gemm_kv(
    const float* __restrict__ Ak, const float* __restrict__ Av,
    const short* __restrict__ Btk, const short* __restrict__ Btv,
    float* __restrict__ kpart, float* __restrict__ vpart) {
  __shared__ __align__(16) short As[128 * 32];
  __shared__ __align__(16) short Bs[128 * 32];
  const int tid = threadIdx.x;
  const int bm = blockIdx.y * 128;
  const int z = blockIdx.z;
  const int kz = z & 3;
  const float* Af = (z >= 4) ? Av : Ak;
  const short* Bt = (z >= 4) ? Btv : Btk;
  float* Cf = ((z >= 4) ? vpart : kpart) + (size_t)kz * (4096 * 128);
  const int K = DD, N = DKV;
  const int w = tid >> 6, lane = tid & 63;
  const int lm = lane & 15, q4 = lane >> 4;
  const int m0 = (w & 1) * 64, n0 = (w >> 1) * 64;

  f32x4 acc[4][4];
#pragma unroll
  for (int mi = 0; mi < 4; ++mi)
#pragma unroll
    for (int ni = 0; ni < 4; ++ni) acc[mi][ni] = (f32x4){0.f, 0.f, 0.f, 0.f};

  const int kbeg = kz * (DD / SPLITK);
  const int kend = kbeg + DD / SPLITK;

  for (int k0 = kbeg; k0 < kend; k0 += 32) {
    __syncthreads();
    {
      float4 av[4];
#pragma unroll
      for (int i = 0; i < 4; ++i) {
        int qd = tid + i * 256;
        int r = qd >> 3, cq = qd & 7;
        av[i] = *(const float4*)(Af + (size_t)(bm + r) * K + k0 + cq * 4);
      }
#pragma unroll
      for (int i = 0; i < 4; ++i) {
        int qd = tid + i * 256;
        int r = qd >> 3, cq = qd & 7;
        int ch = cq >> 1, hf = cq & 1;
        int pc = ch ^ (r & 3);
        bf16x4 t = {f2bf(av[i].x), f2bf(av[i].y), f2bf(av[i].z), f2bf(av[i].w)};
        *(bf16x4*)&As[r * 32 + pc * 8 + hf * 4] = t;
      }
    }
#pragma unroll
    for (int i = 0; i < 2; ++i) {
      int rB = (w * 2 + i) * 16 + (lane >> 2);
      int cB = (lane & 3) ^ (rB & 3);
      async16(Bt + (size_t)rB * K + k0 + cB * 8, &Bs[(w * 2 + i) * 512]);
    }
    __syncthreads();

    bf16x8 af[4], bf[4];
#pragma unroll
    for (int mi = 0; mi < 4; ++mi)
      af[mi] = *(const bf16x8*)&As[(m0 + mi * 16 + lm) * 32 + ((q4 ^ (lm & 3)) * 8)];
#pragma unroll
    for (int ni = 0; ni < 4; ++ni)
      bf[ni] = *(const bf16x8*)&Bs[(n0 + ni * 16 + lm) * 32 + ((q4 ^ (lm & 3)) * 8)];
#pragma unroll
    for (int mi = 0; mi < 4; ++mi)
#pragma unroll
      for (int ni = 0; ni < 4; ++ni)
        acc[mi][ni] = __builtin_amdgcn_mfma_f32_16x16x32_bf16(
            af[mi], bf[ni], acc[mi][ni], 0, 0, 0);
  }

#pragma unroll
  for (int mi = 0; mi < 4; ++mi)
#pragma unroll
    for (int ni = 0; ni < 4; ++ni)
#pragma unroll
      for (int reg = 0; reg < 4; ++reg)
        Cf[(size_t)(bm + m0 + mi * 16 + q4 * 4 + reg) * N +
           (n0 + ni * 16 + lm)] = acc[mi][ni][reg];
}

// ============ KV reduce + bias + K-RoPE + V-transpose + mask bias =========
__global__ __launch_bounds__(256) void kv_reduce(
    const float* __restrict__ kpart, const float* __restrict__ vpart,
    const float* __restrict__ bk, const float* __restrict__ bv,
    short* __restrict__ kp, short* __restrict__ vtb,
    const unsigned char* __restrict__ m, float* __restrict__ mb) {
  __shared__ float Kt[32][128];
  __shared__ short Vl[128][36];
  const int tid = threadIdx.x;
  const int r0 = blockIdx.x * 32;
  if (tid < 32) mb[r0 + tid] = m[r0 + tid] ? -1e30f : 0.0f;
#pragma unroll
  for (int i = 0; i < 16; ++i) {
    int e = tid + i * 256;
    int r = e >> 7, c = e & 127;
    float sk = 0.f, sv = 0.f;
#pragma unroll
    for (int z = 0; z < SPLITK; ++z) {
      sk += kpart[((size_t)z * 4096 + r0 + r) * 128 + c];
      sv += vpart[((size_t)z * 4096 + r0 + r) * 128 + c];
    }
    Kt[r][c] = sk + bk[c];
    Vl[c][r] = f2bf(sv + bv[c]);
  }
  __syncthreads();
#pragma unroll
  for (int i = 0; i < 8; ++i) {
    int e = tid + i * 256;
    int r = e >> 6, d = e & 63;
    float x1 = Kt[r][d], x2 = Kt[r][d + 64];
    float s = (float)((r0 + r) & (SS - 1));
    float ang = s * exp2fast((float)d * (-13.287712379549449f / 64.0f));
    float sn, cs;
    __sincosf(ang, &sn, &cs);
    kp[(size_t)(r0 + r) * 128 + d] = f2bf(x1 * cs - x2 * sn);
    kp[(size_t)(r0 + r) * 128 + d + 64] = f2bf(x1 * sn + x2 * cs);
  }
  const int b = r0 >> 11;
  const int j = tid >> 1, soff = (tid & 1) * 16;
  short* dst = vtb + ((size_t)b * 128 + j) * SS + (r0 & (SS - 1)) + soff;
#pragma unroll
  for (int t = 0; t < 2; ++t) {
    bf16x8 tmp;
#pragma unroll
    for (int u = 0; u < 8; ++u) tmp[u] = Vl[j][soff + t * 8 + u];
    *(bf16x8*)(dst + t * 8) = tmp;
  }
}

// ============ flash attention v11: key-split + 8 waves + fused Q-RoPE =====
#define PSTR 40

__global__ __launch_bounds__(512, 4) void flash_kernel(
    const short* __restrict__ q, const short* __restrict__ k,
    const short* __restrict__ vt, const float* __restrict__ mb,
    short* __restrict__ out, short* __restrict__ pO, float* __restrict__ pL) {
  __shared__ __align__(16) short Kb[2][32 * 128];   // 16 KB
  __shared__ __align__(16) short Vb[2][128 * 64];   // 32 KB
  __shared__ __align__(16) short Ps[8][16 * PSTR];  // 10 KB
  // ---- job decode: size-descending classes, hb fastest ----
  const int j = blockIdx.x;
  const int cls = j >> 5, hb = j & 31;
  int qx, c;
  if (cls < 8) {                       // 8 heavy 32-tile chunks (qx>=8, c=0)
    qx = cls + 8; c = 0;
  } else {
    int kk = (cls - 8) >> 1;
    if ((cls & 1) == 0) { qx = 15 - kk; c = 1; }   // sizes 32,28,...,4
    else                { qx = 7 - kk;  c = 0; }   // sizes 32,28,...,4
  }
  const int h = hb & 15, b = hb >> 4;
  const int kt0 = c ? 32 : 0;
  int kend = 4 * qx + 4;
  if (c == 0 && kend > 32) kend = 32;

  const int tid = threadIdx.x;
  const int w = tid >> 6, lane = tid & 63;
  const int lm = lane & 15, q4 = lane >> 4;
  const int qrow0 = qx * 128 + w * 16;

  // ---- Q fragments (pre-scaled via Wqt; roped here): B[n=q][k=d], ks4 ----
  bf16x8 qf[4];
#pragma unroll
  for (int ks = 0; ks < 4; ++ks)
    qf[ks] = *(const bf16x8*)(q +
        ((size_t)b * SS + qrow0 + lm) * (NHEADS * DKV) + h * DKV +
        ks * 32 + q4 * 8);
  {
    float s = (float)(qrow0 + lm);
#pragma unroll
    for (int ks = 0; ks < 2; ++ks) {
      bf16x8 x1 = qf[ks], x2 = qf[ks + 2];
      bf16x8 y1, y2;
#pragma unroll
      for (int jj = 0; jj < 8; ++jj) {
        int d = ks * 32 + q4 * 8 + jj;
        float ang = s * exp2fast((float)d * (-13.287712379549449f / 64.0f));
        float sn, cs;
        __sincosf(ang, &sn, &cs);
        float a = bf2f(x1[jj]), b2 = bf2f(x2[jj]);
        y1[jj] = f2bf(a * cs - b2 * sn);
        y2[jj] = f2bf(a * sn + b2 * cs);
      }
      qf[ks] = y1;
      qf[ks + 2] = y2;
    }
  }

  bf16x8 onesb;
#pragma unroll
  for (int jj = 0; jj < 8; ++jj) onesb[jj] = (short)0x3F80;

  f32x4 O[8], Ol;
#pragma unroll
  for (int vi = 0; vi < 8; ++vi) O[vi] = (f32x4){0.f, 0.f, 0.f, 0.f};
  Ol = (f32x4){0.f, 0.f, 0.f, 0.f};

  const size_t kbase = (size_t)b * SS;

  // ---- prologue prefetch: K tile kt0 -> Kb[0], V pair {kt0,kt0+1} -> Vb[0]
  {
    {
      int r = w * 4 + (lane >> 4);
      int cc = (lane & 15) ^ (r & 7);
      async16(k + (kbase + (size_t)kt0 * 32 + r) * DKV + cc * 8,
              &Kb[0][w * 512]);
    }
#pragma unroll
    for (int i = 0; i < 2; ++i) {
      int rV = (w * 2 + i) * 8 + (lane >> 3);
      int cV = (lane & 7) ^ (rV & 7);
      async16(vt + ((size_t)b * DKV + rV) * SS + (size_t)kt0 * 32 + cV * 8,
              &Vb[0][(w * 2 + i) * 512]);
    }
  }
  f32x4 mc0 = *(const f32x4*)(mb + kbase + (size_t)kt0 * 32 + q4 * 4);
  f32x4 mc1 = *(const f32x4*)(mb + kbase + (size_t)kt0 * 32 + 16 + q4 * 4);

  for (int kt = kt0; kt < kend; ++kt) {
    __syncthreads();  // drains prefetch for tile kt (in flight since kt-1)

    f32x4 mn0, mn1;
    if (kt + 1 < kend) {
      const int t = kt + 1;
      {
        int r = w * 4 + (lane >> 4);
        int cc = (lane & 15) ^ (r & 7);
        async16(k + (kbase + (size_t)t * 32 + r) * DKV + cc * 8,
                &Kb[t & 1][w * 512]);
      }
      if (kt & 1) {  // t even: stage V pair {t, t+1}
#pragma unroll
        for (int i = 0; i < 2; ++i) {
          int rV = (w * 2 + i) * 8 + (lane >> 3);
          int cV = (lane & 7) ^ (rV & 7);
          async16(vt + ((size_t)b * DKV + rV) * SS + (size_t)t * 32 + cV * 8,
                  &Vb[(t >> 1) & 1][(w * 2 + i) * 512]);
        }
      }
      mn0 = *(const f32x4*)(mb + kbase + (size_t)t * 32 + q4 * 4);
      mn1 = *(const f32x4*)(mb + kbase + (size_t)t * 32 + 16 + q4 * 4);
    }

    // ---- S^T = K (Q*scl)^T : mi2 x ks4 ----
    const short* Kc = Kb[kt & 1];
    f32x4 sacc[2];
#pragma unroll
    for (int mi = 0; mi < 2; ++mi) sacc[mi] = (f32x4){0.f, 0.f, 0.f, 0.f};
#pragma unroll
    for (int mi = 0; mi < 2; ++mi)
#pragma unroll
      for (int ks = 0; ks < 4; ++ks) {
        bf16x8 kf = *(const bf16x8*)&Kc[(mi * 16 + lm) * 128 +
                                        (((ks * 4 + q4) ^ (lm & 7)) << 3)];
        sacc[mi] = __builtin_amdgcn_mfma_f32_16x16x32_bf16(
            kf, qf[ks], sacc[mi], 0, 0, 0);
      }

    // ---- exp2 + b64 P^T writes; causal only on last 4 tiles ----
    const bool diag = (kt >= 4 * qx);
#pragma unroll
    for (int mi = 0; mi < 2; ++mi) {
      f32x4 mbv = mi ? mc1 : mc0;
      float pv[4];
#pragma unroll
      for (int reg = 0; reg < 4; ++reg) {
        float s = sacc[mi][reg] + mbv[reg];
        if (diag) {
          int kg = kt * 32 + mi * 16 + q4 * 4 + reg;
          int qg = qrow0 + lm;
          if (kg > qg) s = -1e30f;
        }
        pv[reg] = exp2fast(s);
      }
      uint2 pkd = {pk2bf(pv[0], pv[1]), pk2bf(pv[2], pv[3])};
      *(uint2*)&Ps[w][lm * PSTR + mi * 16 + q4 * 4] = pkd;
    }
    mc0 = mn0;
    mc1 = mn1;

    // ---- O += P V ; Ol += P 1  (32 keys = one K=32 step) ----
    const short* Vc = Vb[(kt >> 1) & 1];
    const int hf4 = (kt & 1) * 4;
    bf16x8 pf = *(const bf16x8*)&Ps[w][lm * PSTR + q4 * 8];
    Ol = __builtin_amdgcn_mfma_f32_16x16x32_bf16(pf, onesb, Ol, 0, 0, 0);
#pragma unroll
    for (int vi = 0; vi < 8; ++vi) {
      bf16x8 vf = *(const bf16x8*)&Vc[(vi * 16 + lm) * 64 +
                                      (((hf4 + q4) ^ (lm & 7)) << 3)];
      O[vi] = __builtin_amdgcn_mfma_f32_16x16x32_bf16(pf, vf, O[vi], 0, 0, 0);
    }
  }

  // ---- epilogue: scale by 1/l in regs, LDS transpose, uint4 stores ----
  __syncthreads();  // all waves done with Vb; reuse as scratch
  float* Wr = (float*)&Vb[0][0] + w * 544;  // 16 rows x 34 f32 per wave
  float linv[4];
#pragma unroll
  for (int reg = 0; reg < 4; ++reg) linv[reg] = 1.0f / Ol[reg];

  const bool split = (qx >= 8);
  short* obase;
  int ostr;
  if (split) {
    int slot = ((b * 16 + h) * 8 + (qx - 8)) * 2 + c;
    obase = pO + (size_t)slot * (128 * 128);
    ostr = 128;
    if (lm == 0) {
      float* dl = pL + (size_t)slot * 128 + w * 16;
#pragma unroll
      for (int reg = 0; reg < 4; ++reg)
        dl[q4 * 4 + reg] = Ol[reg];
    }
  } else {
    obase = out + ((size_t)b * SS + qx * 128) * (NHEADS * DKV) + h * DKV;
    ostr = NHEADS * DKV;
  }

#pragma unroll
  for (int qd = 0; qd < 4; ++qd) {  // d-quarter = 32 dims (vi pair)
#pragma unroll
    for (int v2 = 0; v2 < 2; ++v2) {
      int vi = qd * 2 + v2;
#pragma unroll
      for (int reg = 0; reg < 4; ++reg)
        Wr[(q4 * 4 + reg) * 34 + v2 * 16 + lm] = O[vi][reg] * linv[reg];
    }
    int r = lane & 15, hh = lane >> 4;
    f32x4 t0 = *(const f32x4*)&Wr[r * 34 + hh * 8];
    f32x4 t1 = *(const f32x4*)&Wr[r * 34 + hh * 8 + 4];
    size_t oaddr = (size_t)(w * 16 + r) * ostr + qd * 32 + hh * 8;
    uint4 o0;
    if (split) {
      o0 = (uint4){pkf16(t0[0], t0[1]), pkf16(t0[2], t0[3]),
                   pkf16(t1[0], t1[1]), pkf16(t1[2], t1[3])};
    } else {
      o0 = (uint4){pk2bf(t0[0], t0[1]), pk2bf(t0[2], t0[3]),
                   pk2bf(t1[0], t1[1]), pk2bf(t1[2], t1[3])};
    }
    *(uint4*)(obase + oaddr) = o0;
  }
}

// ============ combine: O = (O0*l0 + O1*l1)/(l0+l1), fp16 -> bf16 ==========
__global__ __launch_bounds__(256) void combine(
    const short* __restrict__ pO, const float* __restrict__ pL,
    short* __restrict__ out) {
  const int qxi = blockIdx.x, h = blockIdx.y, b = blockIdx.z;
  const int qx = 8 + qxi;
  const int slot2 = ((b * 16 + h) * 8 + qxi) * 2;
  const _Float16* p0 = (const _Float16*)(pO + (size_t)slot2 * (128 * 128));
  const _Float16* p1 = p0 + 128 * 128;
  const float* l0 = pL + (size_t)slot2 * 128;
  const float* l1 = l0 + 128;
  const int t = threadIdx.x;
  const int row = t >> 1, half = t & 1;
  const float w0 = l0[row], w1 = l1[row];
  const float inv = 1.0f / (w0 + w1);
  const float a0 = w0 * inv, a1 = w1 * inv;
  const int off = row * 128 + half * 64;
  short* dst = out + ((size_t)(b * SS + qx * 128 + row)) * (NHEADS * DKV) +
               h * DKV + half * 64;
#pragma unroll
  for (int v = 0; v < 8; ++v) {
    f16x8 x0 = *(const f16x8*)(p0 + off + v * 8);
    f16x8 x1 = *(const f16x8*)(p1 + off + v * 8);
    float r[8];
#pragma unroll
    for (int u = 0; u < 8; ++u)
      r[u] = (float)x0[u] * a0 + (float)x1[u] * a1;
    uint4 o = {pk2bf(r[0], r[1]), pk2bf(r[2], r[3]),
               pk2bf(r[4], r[5]), pk2bf(r[6], r[7])};
    *(uint4*)(dst + v * 8) = o;
  }
}

// ================= launch =================================================
extern "C" void kernel_launch(void* const* d_in, const int* in_sizes, int n_in,
                              void* d_out, int out_size, void* d_ws, size_t ws_size,
                              hipStream_t stream) {
  const float* q_in = (const float*)d_in[0];
  const float* k_in = (const float*)d_in[1];
  const float* v_in = (const float*)d_in[2];
  const unsigned char* mask = (const unsigned char*)d_in[3];
  const float* Wq = (const float*)d_in[4];
  const float* bq = (const float*)d_in[5];
  const float* Wk = (const float*)d_in[6];
  const float* bk = (const float*)d_in[7];
  const float* Wv = (const float*)d_in[8];
  const float* bv = (const float*)d_in[9];
  const float* Wo = (const float*)d_in[10];
  const float* bo = (const float*)d_in[11];

  const int M = BB * SS;  // 4096
  short* Wqt = (short*)d_ws;                   // [2048][2048]
  short* Wot = Wqt + (size_t)DD * DD;          // [2048][2048]
  short* Wkt = Wot + (size_t)DD * DD;          // [128][2048]
  short* Wvt = Wkt + (size_t)DKV * DD;         // [128][2048]
  short* qb  = Wvt + (size_t)DKV * DD;         // [4096][2048] bf16 (input)
  short* qp  = qb + (size_t)M * DD;            // [4096][2048] bf16 (Q proj)
  short* kp  = qp + (size_t)M * DD;            // [4096][128] bf16 (roped K)
  short* vtb = kp + (size_t)M * DKV;           // [2][128][2048] bf16 (V^T)
  float* mb  = (float*)(vtb + (size_t)BB * DKV * SS);  // [2][2048]
  float* kpart = mb + (size_t)BB * SS;         // [4][4096][128]
  float* vpart = kpart + (size_t)SPLITK * M * DKV;
  float* pL = vpart + (size_t)SPLITK * M * DKV;  // [512][128] f32
  short* ap = qb;  // alias: qb dead after Q-proj; flash output reuses it
  // fp16 partials alias kpart+vpart (dead after kv_reduce): 512 slots x 32KB
  short* pO = (short*)kpart;

  cvt_q<<<M * DD / (8 * 256), 256, 0, stream>>>(q_in, qb);
  transpose_w2<<<dim3(DD / 32, DD / 32, 2), 256, 0, stream>>>(
      Wq, Wqt, Wo, Wot, DD, DD, QSCL, 1.0f);
  transpose_w2<<<dim3(DKV / 32, DD / 32, 2), 256, 0, stream>>>(
      Wk, Wkt, Wv, Wvt, DD, DKV, 1.0f, 1.0f);

  gemm_kv<<<dim3(1, M / 128, 2 * SPLITK), 256, 0, stream>>>(
      k_in, v_in, Wkt, Wvt, kpart, vpart);
  gemm_as<1><<<dim3(DD / 128, M / 128, 1), 256, 0, stream>>>(
      qb, Wqt, bq, qp, M, DD, DD, DD, 1, QSCL);
  kv_reduce<<<M / 32, 256, 0, stream>>>(kpart, vpart, bk, bv, kp, vtb, mask, mb);

  flash_kernel<<<dim3(768), 512, 0, stream>>>(qp, kp, vtb, mb, ap, pO, pL);
  combine<<<dim3(8, NHEADS, BB), 256, 0, stream>>>(pO, pL, ap);

  gemm_as<1><<<dim3(DD / 128, M / 128, 1), 256, 0, stream>>>(
      ap, Wot, bo, d_out, M, DD, DD, DD, 0, 1.0f);
}

// Round 9
// 363.359 us; speedup vs baseline: 1.1563x; 1.0670x over previous
//
#include <hip/hip_runtime.h>

#define NHEADS 16
#define DKV 128
#define BB 2
#define SS 2048
#define DD 2048

typedef __attribute__((ext_vector_type(8))) short bf16x8;
typedef __attribute__((ext_vector_type(4))) short bf16x4;
typedef __attribute__((ext_vector_type(4))) float f32x4;
typedef __attribute__((ext_vector_type(8))) _Float16 f16x8;

// scale 1/sqrt(128) * log2(e)  (we use exp2 instead of exp)
#define QSCL 0.12752775f

__device__ __forceinline__ short f2bf(float x) {
  unsigned u = __builtin_bit_cast(unsigned, x);
  unsigned r = (u + 0x7fffu + ((u >> 16) & 1u)) >> 16;  // RTNE
  return (short)(unsigned short)r;
}
__device__ __forceinline__ float bf2f(short s) {
  unsigned u = ((unsigned)(unsigned short)s) << 16;
  return __builtin_bit_cast(float, u);
}
__device__ __forceinline__ unsigned pk2bf(float a, float b) {
#if __has_builtin(__builtin_amdgcn_cvt_pk_bf16_f32)
  typedef __attribute__((ext_vector_type(2))) __bf16 bf2_t;
  bf2_t r = __builtin_amdgcn_cvt_pk_bf16_f32(a, b);
  return __builtin_bit_cast(unsigned, r);
#else
  unsigned ua = __builtin_bit_cast(unsigned, a);
  unsigned ub = __builtin_bit_cast(unsigned, b);
  return ((ua + 0x8000u) >> 16) | ((ub + 0x8000u) & 0xffff0000u);
#endif
}
__device__ __forceinline__ unsigned pkf16(float a, float b) {
#if __has_builtin(__builtin_amdgcn_cvt_pkrtz)
  typedef __attribute__((ext_vector_type(2))) __fp16 h2_t;
  h2_t r = __builtin_amdgcn_cvt_pkrtz(a, b);
  return __builtin_bit_cast(unsigned, r);
#else
  _Float16 ha = (_Float16)a, hb = (_Float16)b;
  unsigned short ua = __builtin_bit_cast(unsigned short, ha);
  unsigned short ub = __builtin_bit_cast(unsigned short, hb);
  return (unsigned)ua | ((unsigned)ub << 16);
#endif
}
__device__ __forceinline__ float exp2fast(float x) {
#if __has_builtin(__builtin_amdgcn_exp2f)
  return __builtin_amdgcn_exp2f(x);
#else
  return exp2f(x);
#endif
}

// async global->LDS, 16B/lane; lds dst = wave-uniform base + lane*16
__device__ __forceinline__ void async16(const void* g, void* l) {
  __builtin_amdgcn_global_load_lds(
      (__attribute__((address_space(1))) void*)g,
      (__attribute__((address_space(3))) void*)l, 16, 0, 0);
}

// ============ prep: fused cvt_q + 4 weight transposes =====================
// id < 4096: q_in fp32 -> qb bf16 (8 elems/thread)
// 4096..12287: transpose Wq (z=0, *QSCL) / Wo (z=1), 64x64 tile grid each
// 12288..12799: transpose Wk (z=0) / Wv (z=1), 4x64 tile grid each
__global__ __launch_bounds__(256) void prep(
    const float* __restrict__ q_in, short* __restrict__ qb,
    const float* __restrict__ Wq, short* __restrict__ Wqt,
    const float* __restrict__ Wo, short* __restrict__ Wot,
    const float* __restrict__ Wk, short* __restrict__ Wkt,
    const float* __restrict__ Wv, short* __restrict__ Wvt) {
  const int id = blockIdx.x;
  if (id < 4096) {
    int idx = id * 256 + threadIdx.x;
    int g = idx * 8;
    float4 a = *(const float4*)(q_in + g);
    float4 b = *(const float4*)(q_in + g + 4);
    uint4 o = {pk2bf(a.x, a.y), pk2bf(a.z, a.w), pk2bf(b.x, b.y),
               pk2bf(b.z, b.w)};
    *(uint4*)(qb + g) = o;
    return;
  }
  __shared__ float T[32][33];
  const float* W;
  short* Wt;
  float scale = 1.0f;
  int N, bx, by;
  if (id < 12288) {
    int Lt = id - 4096;
    int z = Lt >> 12;
    int rem = Lt & 4095;
    bx = rem & 63;
    by = rem >> 6;
    N = DD;
    if (z == 0) { W = Wq; Wt = Wqt; scale = QSCL; }
    else        { W = Wo; Wt = Wot; }
  } else {
    int Ls = id - 12288;
    int z = Ls >> 8;
    int rem = Ls & 255;
    bx = rem & 3;
    by = rem >> 2;
    N = DKV;
    if (z == 0) { W = Wk; Wt = Wkt; }
    else        { W = Wv; Wt = Wvt; }
  }
  const int K = DD;
  const int nt = bx * 32;
  const int kt = by * 32;
  const int tx = threadIdx.x & 31;
  const int ty = threadIdx.x >> 5;
#pragma unroll
  for (int i = 0; i < 4; ++i)
    T[ty + i * 8][tx] = W[(size_t)(kt + ty + i * 8) * N + nt + tx];
  __syncthreads();
#pragma unroll
  for (int i = 0; i < 4; ++i)
    Wt[(size_t)(nt + ty + i * 8) * K + kt + tx] = f2bf(T[tx][ty + i * 8] * scale);
}

// ============ MFMA GEMM with async staging (O-projection) =================
// XCD-aware block remap for the 512-block (16x32) launch: default linear id
// L = x + 16y round-robins XCD = L%8 = x%8 -> every XCD touches all 32
// A-row-panels. Remap gives each XCD an 8x8 tile rectangle (L2-sized).
template <int AMODE>
__global__ __launch_bounds__(256) void gemm_as(
    const void* __restrict__ Ap, const short* __restrict__ Bt,
    const float* __restrict__ bias, void* __restrict__ Cp,
    int M, int N, int K, int KC, int cmode, float bscale) {
  __shared__ __align__(16) short As[128 * 32];
  __shared__ __align__(16) short Bs[128 * 32];
  const int tid = threadIdx.x;
  int bxi = blockIdx.x, byi = blockIdx.y;
  if (gridDim.x == 16 && gridDim.y == 32) {
    int L = byi * 16 + bxi;
    int i = L & 7, t = L >> 3;
    byi = 8 * (i >> 1) + (t & 7);
    bxi = 2 * (t >> 3) + (i & 1);
  }
  const int bm = byi * 128;
  const int bn = bxi * 128;
  const int kz = blockIdx.z;
  const int w = tid >> 6, lane = tid & 63;
  const int lm = lane & 15, q4 = lane >> 4;
  const int m0 = (w & 1) * 64, n0 = (w >> 1) * 64;

  f32x4 acc[4][4];
#pragma unroll
  for (int mi = 0; mi < 4; ++mi)
#pragma unroll
    for (int ni = 0; ni < 4; ++ni) acc[mi][ni] = (f32x4){0.f, 0.f, 0.f, 0.f};

  const int kbeg = kz * KC;
  const int kend = kbeg + KC;

  for (int k0 = kbeg; k0 < kend; k0 += 32) {
    __syncthreads();
    if (AMODE == 1) {
      const short* Ab = (const short*)Ap;
#pragma unroll
      for (int i = 0; i < 2; ++i) {
        int rA = (w * 2 + i) * 16 + (lane >> 2);
        int cA = (lane & 3) ^ (rA & 3);
        async16(Ab + (size_t)(bm + rA) * K + k0 + cA * 8, &As[(w * 2 + i) * 512]);
      }
    } else {
      const float* Af = (const float*)Ap;
      float4 av[4];
#pragma unroll
      for (int i = 0; i < 4; ++i) {
        int qd = tid + i * 256;
        int r = qd >> 3, cq = qd & 7;
        av[i] = *(const float4*)(Af + (size_t)(bm + r) * K + k0 + cq * 4);
      }
#pragma unroll
      for (int i = 0; i < 4; ++i) {
        int qd = tid + i * 256;
        int r = qd >> 3, cq = qd & 7;
        int ch = cq >> 1, hf = cq & 1;
        int pc = ch ^ (r & 3);
        bf16x4 t = {f2bf(av[i].x), f2bf(av[i].y), f2bf(av[i].z), f2bf(av[i].w)};
        *(bf16x4*)&As[r * 32 + pc * 8 + hf * 4] = t;
      }
    }
#pragma unroll
    for (int i = 0; i < 2; ++i) {
      int rB = (w * 2 + i) * 16 + (lane >> 2);
      int cB = (lane & 3) ^ (rB & 3);
      async16(Bt + (size_t)(bn + rB) * K + k0 + cB * 8, &Bs[(w * 2 + i) * 512]);
    }
    __syncthreads();

    bf16x8 af[4], bf[4];
#pragma unroll
    for (int mi = 0; mi < 4; ++mi)
      af[mi] = *(const bf16x8*)&As[(m0 + mi * 16 + lm) * 32 + ((q4 ^ (lm & 3)) * 8)];
#pragma unroll
    for (int ni = 0; ni < 4; ++ni)
      bf[ni] = *(const bf16x8*)&Bs[(n0 + ni * 16 + lm) * 32 + ((q4 ^ (lm & 3)) * 8)];
#pragma unroll
    for (int mi = 0; mi < 4; ++mi)
#pragma unroll
      for (int ni = 0; ni < 4; ++ni)
        acc[mi][ni] = __builtin_amdgcn_mfma_f32_16x16x32_bf16(
            af[mi], bf[ni], acc[mi][ni], 0, 0, 0);
  }

  if (cmode == 2) {
    float* Cf = (float*)Cp + (size_t)kz * M * N;
#pragma unroll
    for (int mi = 0; mi < 4; ++mi)
#pragma unroll
      for (int ni = 0; ni < 4; ++ni)
#pragma unroll
        for (int reg = 0; reg < 4; ++reg)
          Cf[(size_t)(bm + m0 + mi * 16 + q4 * 4 + reg) * N +
             (bn + n0 + ni * 16 + lm)] = acc[mi][ni][reg];
  } else {
#pragma unroll
    for (int mi = 0; mi < 4; ++mi)
#pragma unroll
      for (int ni = 0; ni < 4; ++ni)
#pragma unroll
        for (int reg = 0; reg < 4; ++reg) {
          int rowg = bm + m0 + mi * 16 + q4 * 4 + reg;
          int colg = bn + n0 + ni * 16 + lm;
          float val = acc[mi][ni][reg] + bias[colg] * bscale;
          if (cmode == 0)
            ((float*)Cp)[(size_t)rowg * N + colg] = val;
          else
            ((short*)Cp)[(size_t)rowg * N + colg] = f2bf(val);
        }
  }
}

// ============ merged KV-projection + Q-projection, one 768-block launch ===
// id < 256: KV split-K partials (ym-major: XCD = id%8 = ym%8 -> each XCD
//   reads 4 A-row-panels of k_in+v_in, L2-friendly). Exact gemm_kv body.
// id >= 256: Q-proj AMODE=1 with XCD remap (offset 256 == 0 mod 8).
#define SPLITK 4
__global__ __launch_bounds__(256) void gemm_qkv(
    const float* __restrict__ k_in, const float* __restrict__ v_in,
    const short* __restrict__ Btk, const short* __restrict__ Btv,
    float* __restrict__ kpart, float* __restrict__ vpart,
    const short* __restrict__ qb, const short* __restrict__ Wqt,
    const float* __restrict__ bq, short* __restrict__ qp) {
  __shared__ __align__(16) short As[128 * 32];
  __shared__ __align__(16) short Bs[128 * 32];
  const int tid = threadIdx.x;
  const int w = tid >> 6, lane = tid & 63;
  const int lm = lane & 15, q4 = lane >> 4;
  const int m0 = (w & 1) * 64, n0 = (w >> 1) * 64;
  const int id = blockIdx.x;

  f32x4 acc[4][4];
#pragma unroll
  for (int mi = 0; mi < 4; ++mi)
#pragma unroll
    for (int ni = 0; ni < 4; ++ni) acc[mi][ni] = (f32x4){0.f, 0.f, 0.f, 0.f};

  if (id < 256) {
    const int ym = id & 31, zz = id >> 5;
    const int kz = zz & 3;
    const float* Af = (zz >= 4) ? v_in : k_in;
    const short* Bt = (zz >= 4) ? Btv : Btk;
    float* Cf = ((zz >= 4) ? vpart : kpart) + (size_t)kz * (4096 * 128);
    const int bm = ym * 128;
    const int K = DD, N = DKV;
    const int kbeg = kz * (DD / SPLITK);
    const int kend = kbeg + DD / SPLITK;

    for (int k0 = kbeg; k0 < kend; k0 += 32) {
      __syncthreads();
      {
        float4 av[4];
#pragma unroll
        for (int i = 0; i < 4; ++i) {
          int qd = tid + i * 256;
          int r = qd >> 3, cq = qd & 7;
          av[i] = *(const float4*)(Af + (size_t)(bm + r) * K + k0 + cq * 4);
        }
#pragma unroll
        for (int i = 0; i < 4; ++i) {
          int qd = tid + i * 256;
          int r = qd >> 3, cq = qd & 7;
          int ch = cq >> 1, hf = cq & 1;
          int pc = ch ^ (r & 3);
          bf16x4 t = {f2bf(av[i].x), f2bf(av[i].y), f2bf(av[i].z), f2bf(av[i].w)};
          *(bf16x4*)&As[r * 32 + pc * 8 + hf * 4] = t;
        }
      }
#pragma unroll
      for (int i = 0; i < 2; ++i) {
        int rB = (w * 2 + i) * 16 + (lane >> 2);
        int cB = (lane & 3) ^ (rB & 3);
        async16(Bt + (size_t)rB * K + k0 + cB * 8, &Bs[(w * 2 + i) * 512]);
      }
      __syncthreads();

      bf16x8 af[4], bf[4];
#pragma unroll
      for (int mi = 0; mi < 4; ++mi)
        af[mi] = *(const bf16x8*)&As[(m0 + mi * 16 + lm) * 32 + ((q4 ^ (lm & 3)) * 8)];
#pragma unroll
      for (int ni = 0; ni < 4; ++ni)
        bf[ni] = *(const bf16x8*)&Bs[(n0 + ni * 16 + lm) * 32 + ((q4 ^ (lm & 3)) * 8)];
#pragma unroll
      for (int mi = 0; mi < 4; ++mi)
#pragma unroll
        for (int ni = 0; ni < 4; ++ni)
          acc[mi][ni] = __builtin_amdgcn_mfma_f32_16x16x32_bf16(
              af[mi], bf[ni], acc[mi][ni], 0, 0, 0);
    }

#pragma unroll
    for (int mi = 0; mi < 4; ++mi)
#pragma unroll
      for (int ni = 0; ni < 4; ++ni)
#pragma unroll
        for (int reg = 0; reg < 4; ++reg)
          Cf[(size_t)(bm + m0 + mi * 16 + q4 * 4 + reg) * N +
             (n0 + ni * 16 + lm)] = acc[mi][ni][reg];
  } else {
    int L = id - 256;
    int i2 = L & 7, t2 = L >> 3;
    const int byi = 8 * (i2 >> 1) + (t2 & 7);
    const int bxi = 2 * (t2 >> 3) + (i2 & 1);
    const int bm = byi * 128;
    const int bn = bxi * 128;
    const int K = DD, N = DD;

    for (int k0 = 0; k0 < DD; k0 += 32) {
      __syncthreads();
#pragma unroll
      for (int i = 0; i < 2; ++i) {
        int rA = (w * 2 + i) * 16 + (lane >> 2);
        int cA = (lane & 3) ^ (rA & 3);
        async16(qb + (size_t)(bm + rA) * K + k0 + cA * 8, &As[(w * 2 + i) * 512]);
      }
#pragma unroll
      for (int i = 0; i < 2; ++i) {
        int rB = (w * 2 + i) * 16 + (lane >> 2);
        int cB = (lane & 3) ^ (rB & 3);
        async16(Wqt + (size_t)(bn + rB) * K + k0 + cB * 8, &Bs[(w * 2 + i) * 512]);
      }
      __syncthreads();

      bf16x8 af[4], bf[4];
#pragma unroll
      for (int mi = 0; mi < 4; ++mi)
        af[mi] = *(const bf16x8*)&As[(m0 + mi * 16 + lm) * 32 + ((q4 ^ (lm & 3)) * 8)];
#pragma unroll
      for (int ni = 0; ni < 4; ++ni)
        bf[ni] = *(const bf16x8*)&Bs[(n0 + ni * 16 + lm) * 32 + ((q4 ^ (lm & 3)) * 8)];
#pragma unroll
      for (int mi = 0; mi < 4; ++mi)
#pragma unroll
        for (int ni = 0; ni < 4; ++ni)
          acc[mi][ni] = __builtin_amdgcn_mfma_f32_16x16x32_bf16(
              af[mi], bf[ni], acc[mi][ni], 0, 0, 0);
    }

#pragma unroll
    for (int mi = 0; mi < 4; ++mi)
#pragma unroll
      for (int ni = 0; ni < 4; ++ni)
#pragma unroll
        for (int reg = 0; reg < 4; ++reg) {
          int rowg = bm + m0 + mi * 16 + q4 * 4 + reg;
          int colg = bn + n0 + ni * 16 + lm;
          qp[(size_t)rowg * N + colg] =
              f2bf(acc[mi][ni][reg] + bq[colg] * QSCL);
        }
  }
}

// ============ KV reduce (16 rows/block) + bias + K-RoPE + V^T + mask ======
__global__ __launch_bounds__(256) void kv_reduce(
    const float* __restrict__ kpart, const float* __restrict__ vpart,
    const float* __restrict__ bk, const float* __restrict__ bv,
    short* __restrict__ kp, short* __restrict__ vtb,
    const unsigned char* __restrict__ m, float* __restrict__ mb) {
  __shared__ float Kt[16][128];
  __shared__ short Vl[128][18];
  const int tid = threadIdx.x;
  const int r0 = blockIdx.x * 16;
  if (tid < 16) mb[r0 + tid] = m[r0 + tid] ? -1e30f : 0.0f;
#pragma unroll
  for (int i = 0; i < 8; ++i) {
    int e = tid + i * 256;
    int r = e >> 7, c = e & 127;
    float sk = 0.f, sv = 0.f;
#pragma unroll
    for (int z = 0; z < SPLITK; ++z) {
      sk += kpart[((size_t)z * 4096 + r0 + r) * 128 + c];
      sv += vpart[((size_t)z * 4096 + r0 + r) * 128 + c];
    }
    Kt[r][c] = sk + bk[c];
    Vl[c][r] = f2bf(sv + bv[c]);
  }
  __syncthreads();
#pragma unroll
  for (int i = 0; i < 4; ++i) {
    int e = tid + i * 256;
    int r = e >> 6, d = e & 63;
    float x1 = Kt[r][d], x2 = Kt[r][d + 64];
    float s = (float)((r0 + r) & (SS - 1));
    float ang = s * exp2fast((float)d * (-13.287712379549449f / 64.0f));
    float sn, cs;
    __sincosf(ang, &sn, &cs);
    kp[(size_t)(r0 + r) * 128 + d] = f2bf(x1 * cs - x2 * sn);
    kp[(size_t)(r0 + r) * 128 + d + 64] = f2bf(x1 * sn + x2 * cs);
  }
  const int b = r0 >> 11;
  const int j = tid >> 1, soff = (tid & 1) * 8;
  short* dst = vtb + ((size_t)b * 128 + j) * SS + (r0 & (SS - 1)) + soff;
  bf16x8 tmp;
#pragma unroll
  for (int u = 0; u < 8; ++u) tmp[u] = Vl[j][soff + u];
  *(bf16x8*)dst = tmp;
}

// ============ flash attention v11: key-split + 8 waves + fused Q-RoPE =====
#define PSTR 40

__global__ __launch_bounds__(512, 4) void flash_kernel(
    const short* __restrict__ q, const short* __restrict__ k,
    const short* __restrict__ vt, const float* __restrict__ mb,
    short* __restrict__ out, short* __restrict__ pO, float* __restrict__ pL) {
  __shared__ __align__(16) short Kb[2][32 * 128];   // 16 KB
  __shared__ __align__(16) short Vb[2][128 * 64];   // 32 KB
  __shared__ __align__(16) short Ps[8][16 * PSTR];  // 10 KB
  // ---- job decode: size-descending classes, hb fastest ----
  const int j = blockIdx.x;
  const int cls = j >> 5, hb = j & 31;
  int qx, c;
  if (cls < 8) {                       // 8 heavy 32-tile chunks (qx>=8, c=0)
    qx = cls + 8; c = 0;
  } else {
    int kk = (cls - 8) >> 1;
    if ((cls & 1) == 0) { qx = 15 - kk; c = 1; }   // sizes 32,28,...,4
    else                { qx = 7 - kk;  c = 0; }   // sizes 32,28,...,4
  }
  const int h = hb & 15, b = hb >> 4;
  const int kt0 = c ? 32 : 0;
  int kend = 4 * qx + 4;
  if (c == 0 && kend > 32) kend = 32;

  const int tid = threadIdx.x;
  const int w = tid >> 6, lane = tid & 63;
  const int lm = lane & 15, q4 = lane >> 4;
  const int qrow0 = qx * 128 + w * 16;

  // ---- Q fragments (pre-scaled via Wqt; roped here): B[n=q][k=d], ks4 ----
  bf16x8 qf[4];
#pragma unroll
  for (int ks = 0; ks < 4; ++ks)
    qf[ks] = *(const bf16x8*)(q +
        ((size_t)b * SS + qrow0 + lm) * (NHEADS * DKV) + h * DKV +
        ks * 32 + q4 * 8);
  {
    float s = (float)(qrow0 + lm);
#pragma unroll
    for (int ks = 0; ks < 2; ++ks) {
      bf16x8 x1 = qf[ks], x2 = qf[ks + 2];
      bf16x8 y1, y2;
#pragma unroll
      for (int jj = 0; jj < 8; ++jj) {
        int d = ks * 32 + q4 * 8 + jj;
        float ang = s * exp2fast((float)d * (-13.287712379549449f / 64.0f));
        float sn, cs;
        __sincosf(ang, &sn, &cs);
        float a = bf2f(x1[jj]), b2 = bf2f(x2[jj]);
        y1[jj] = f2bf(a * cs - b2 * sn);
        y2[jj] = f2bf(a * sn + b2 * cs);
      }
      qf[ks] = y1;
      qf[ks + 2] = y2;
    }
  }

  bf16x8 onesb;
#pragma unroll
  for (int jj = 0; jj < 8; ++jj) onesb[jj] = (short)0x3F80;

  f32x4 O[8], Ol;
#pragma unroll
  for (int vi = 0; vi < 8; ++vi) O[vi] = (f32x4){0.f, 0.f, 0.f, 0.f};
  Ol = (f32x4){0.f, 0.f, 0.f, 0.f};

  const size_t kbase = (size_t)b * SS;

  // ---- prologue prefetch: K tile kt0 -> Kb[0], V pair {kt0,kt0+1} -> Vb[0]
  {
    {
      int r = w * 4 + (lane >> 4);
      int cc = (lane & 15) ^ (r & 7);
      async16(k + (kbase + (size_t)kt0 * 32 + r) * DKV + cc * 8,
              &Kb[0][w * 512]);
    }
#pragma unroll
    for (int i = 0; i < 2; ++i) {
      int rV = (w * 2 + i) * 8 + (lane >> 3);
      int cV = (lane & 7) ^ (rV & 7);
      async16(vt + ((size_t)b * DKV + rV) * SS + (size_t)kt0 * 32 + cV * 8,
              &Vb[0][(w * 2 + i) * 512]);
    }
  }
  f32x4 mc0 = *(const f32x4*)(mb + kbase + (size_t)kt0 * 32 + q4 * 4);
  f32x4 mc1 = *(const f32x4*)(mb + kbase + (size_t)kt0 * 32 + 16 + q4 * 4);

  for (int kt = kt0; kt < kend; ++kt) {
    __syncthreads();  // drains prefetch for tile kt (in flight since kt-1)

    f32x4 mn0, mn1;
    if (kt + 1 < kend) {
      const int t = kt + 1;
      {
        int r = w * 4 + (lane >> 4);
        int cc = (lane & 15) ^ (r & 7);
        async16(k + (kbase + (size_t)t * 32 + r) * DKV + cc * 8,
                &Kb[t & 1][w * 512]);
      }
      if (kt & 1) {  // t even: stage V pair {t, t+1}
#pragma unroll
        for (int i = 0; i < 2; ++i) {
          int rV = (w * 2 + i) * 8 + (lane >> 3);
          int cV = (lane & 7) ^ (rV & 7);
          async16(vt + ((size_t)b * DKV + rV) * SS + (size_t)t * 32 + cV * 8,
                  &Vb[(t >> 1) & 1][(w * 2 + i) * 512]);
        }
      }
      mn0 = *(const f32x4*)(mb + kbase + (size_t)t * 32 + q4 * 4);
      mn1 = *(const f32x4*)(mb + kbase + (size_t)t * 32 + 16 + q4 * 4);
    }

    // ---- S^T = K (Q*scl)^T : mi2 x ks4 ----
    const short* Kc = Kb[kt & 1];
    f32x4 sacc[2];
#pragma unroll
    for (int mi = 0; mi < 2; ++mi) sacc[mi] = (f32x4){0.f, 0.f, 0.f, 0.f};
#pragma unroll
    for (int mi = 0; mi < 2; ++mi)
#pragma unroll
      for (int ks = 0; ks < 4; ++ks) {
        bf16x8 kf = *(const bf16x8*)&Kc[(mi * 16 + lm) * 128 +
                                        (((ks * 4 + q4) ^ (lm & 7)) << 3)];
        sacc[mi] = __builtin_amdgcn_mfma_f32_16x16x32_bf16(
            kf, qf[ks], sacc[mi], 0, 0, 0);
      }

    // ---- exp2 + b64 P^T writes; causal only on last 4 tiles ----
    const bool diag = (kt >= 4 * qx);
#pragma unroll
    for (int mi = 0; mi < 2; ++mi) {
      f32x4 mbv = mi ? mc1 : mc0;
      float pv[4];
#pragma unroll
      for (int reg = 0; reg < 4; ++reg) {
        float s = sacc[mi][reg] + mbv[reg];
        if (diag) {
          int kg = kt * 32 + mi * 16 + q4 * 4 + reg;
          int qg = qrow0 + lm;
          if (kg > qg) s = -1e30f;
        }
        pv[reg] = exp2fast(s);
      }
      uint2 pkd = {pk2bf(pv[0], pv[1]), pk2bf(pv[2], pv[3])};
      *(uint2*)&Ps[w][lm * PSTR + mi * 16 + q4 * 4] = pkd;
    }
    mc0 = mn0;
    mc1 = mn1;

    // ---- O += P V ; Ol += P 1  (32 keys = one K=32 step) ----
    const short* Vc = Vb[(kt >> 1) & 1];
    const int hf4 = (kt & 1) * 4;
    bf16x8 pf = *(const bf16x8*)&Ps[w][lm * PSTR + q4 * 8];
    Ol = __builtin_amdgcn_mfma_f32_16x16x32_bf16(pf, onesb, Ol, 0, 0, 0);
#pragma unroll
    for (int vi = 0; vi < 8; ++vi) {
      bf16x8 vf = *(const bf16x8*)&Vc[(vi * 16 + lm) * 64 +
                                      (((hf4 + q4) ^ (lm & 7)) << 3)];
      O[vi] = __builtin_amdgcn_mfma_f32_16x16x32_bf16(pf, vf, O[vi], 0, 0, 0);
    }
  }

  // ---- epilogue: scale by 1/l in regs, LDS transpose, uint4 stores ----
  __syncthreads();  // all waves done with Vb; reuse as scratch
  float* Wr = (float*)&Vb[0][0] + w * 544;  // 16 rows x 34 f32 per wave
  float linv[4];
#pragma unroll
  for (int reg = 0; reg < 4; ++reg) linv[reg] = 1.0f / Ol[reg];

  const bool split = (qx >= 8);
  short* obase;
  int ostr;
  if (split) {
    int slot = ((b * 16 + h) * 8 + (qx - 8)) * 2 + c;
    obase = pO + (size_t)slot * (128 * 128);
    ostr = 128;
    if (lm == 0) {
      float* dl = pL + (size_t)slot * 128 + w * 16;
#pragma unroll
      for (int reg = 0; reg < 4; ++reg)
        dl[q4 * 4 + reg] = Ol[reg];
    }
  } else {
    obase = out + ((size_t)b * SS + qx * 128) * (NHEADS * DKV) + h * DKV;
    ostr = NHEADS * DKV;
  }

#pragma unroll
  for (int qd = 0; qd < 4; ++qd) {  // d-quarter = 32 dims (vi pair)
#pragma unroll
    for (int v2 = 0; v2 < 2; ++v2) {
      int vi = qd * 2 + v2;
#pragma unroll
      for (int reg = 0; reg < 4; ++reg)
        Wr[(q4 * 4 + reg) * 34 + v2 * 16 + lm] = O[vi][reg] * linv[reg];
    }
    int r = lane & 15, hh = lane >> 4;
    f32x4 t0 = *(const f32x4*)&Wr[r * 34 + hh * 8];
    f32x4 t1 = *(const f32x4*)&Wr[r * 34 + hh * 8 + 4];
    size_t oaddr = (size_t)(w * 16 + r) * ostr + qd * 32 + hh * 8;
    uint4 o0;
    if (split) {
      o0 = (uint4){pkf16(t0[0], t0[1]), pkf16(t0[2], t0[3]),
                   pkf16(t1[0], t1[1]), pkf16(t1[2], t1[3])};
    } else {
      o0 = (uint4){pk2bf(t0[0], t0[1]), pk2bf(t0[2], t0[3]),
                   pk2bf(t1[0], t1[1]), pk2bf(t1[2], t1[3])};
    }
    *(uint4*)(obase + oaddr) = o0;
  }
}

// ============ combine: O = (O0*l0 + O1*l1)/(l0+l1), fp16 -> bf16 ==========
__global__ __launch_bounds__(256) void combine(
    const short* __restrict__ pO, const float* __restrict__ pL,
    short* __restrict__ out) {
  const int qxi = blockIdx.x, h = blockIdx.y, b = blockIdx.z;
  const int qx = 8 + qxi;
  const int slot2 = ((b * 16 + h) * 8 + qxi) * 2;
  const _Float16* p0 = (const _Float16*)(pO + (size_t)slot2 * (128 * 128));
  const _Float16* p1 = p0 + 128 * 128;
  const float* l0 = pL + (size_t)slot2 * 128;
  const float* l1 = l0 + 128;
  const int t = threadIdx.x;
  const int row = t >> 1, half = t & 1;
  const float w0 = l0[row], w1 = l1[row];
  const float inv = 1.0f / (w0 + w1);
  const float a0 = w0 * inv, a1 = w1 * inv;
  const int off = row * 128 + half * 64;
  short* dst = out + ((size_t)(b * SS + qx * 128 + row)) * (NHEADS * DKV) +
               h * DKV + half * 64;
#pragma unroll
  for (int v = 0; v < 8; ++v) {
    f16x8 x0 = *(const f16x8*)(p0 + off + v * 8);
    f16x8 x1 = *(const f16x8*)(p1 + off + v * 8);
    float r[8];
#pragma unroll
    for (int u = 0; u < 8; ++u)
      r[u] = (float)x0[u] * a0 + (float)x1[u] * a1;
    uint4 o = {pk2bf(r[0], r[1]), pk2bf(r[2], r[3]),
               pk2bf(r[4], r[5]), pk2bf(r[6], r[7])};
    *(uint4*)(dst + v * 8) = o;
  }
}

// ================= launch =================================================
extern "C" void kernel_launch(void* const* d_in, const int* in_sizes, int n_in,
                              void* d_out, int out_size, void* d_ws, size_t ws_size,
                              hipStream_t stream) {
  const float* q_in = (const float*)d_in[0];
  const float* k_in = (const float*)d_in[1];
  const float* v_in = (const float*)d_in[2];
  const unsigned char* mask = (const unsigned char*)d_in[3];
  const float* Wq = (const float*)d_in[4];
  const float* bq = (const float*)d_in[5];
  const float* Wk = (const float*)d_in[6];
  const float* bk = (const float*)d_in[7];
  const float* Wv = (const float*)d_in[8];
  const float* bv = (const float*)d_in[9];
  const float* Wo = (const float*)d_in[10];
  const float* bo = (const float*)d_in[11];

  const int M = BB * SS;  // 4096
  short* Wqt = (short*)d_ws;                   // [2048][2048]
  short* Wot = Wqt + (size_t)DD * DD;          // [2048][2048]
  short* Wkt = Wot + (size_t)DD * DD;          // [128][2048]
  short* Wvt = Wkt + (size_t)DKV * DD;         // [128][2048]
  short* qb  = Wvt + (size_t)DKV * DD;         // [4096][2048] bf16 (input)
  short* qp  = qb + (size_t)M * DD;            // [4096][2048] bf16 (Q proj)
  short* kp  = qp + (size_t)M * DD;            // [4096][128] bf16 (roped K)
  short* vtb = kp + (size_t)M * DKV;           // [2][128][2048] bf16 (V^T)
  float* mb  = (float*)(vtb + (size_t)BB * DKV * SS);  // [2][2048]
  float* kpart = mb + (size_t)BB * SS;         // [4][4096][128]
  float* vpart = kpart + (size_t)SPLITK * M * DKV;
  float* pL = vpart + (size_t)SPLITK * M * DKV;  // [512][128] f32
  short* ap = qb;  // alias: qb dead after Q-proj; flash output reuses it
  // fp16 partials alias kpart+vpart (dead after kv_reduce): 512 slots x 32KB
  short* pO = (short*)kpart;

  prep<<<12800, 256, 0, stream>>>(q_in, qb, Wq, Wqt, Wo, Wot, Wk, Wkt, Wv, Wvt);

  gemm_qkv<<<768, 256, 0, stream>>>(k_in, v_in, Wkt, Wvt, kpart, vpart,
                                    qb, Wqt, bq, qp);
  kv_reduce<<<M / 16, 256, 0, stream>>>(kpart, vpart, bk, bv, kp, vtb, mask, mb);

  flash_kernel<<<dim3(768), 512, 0, stream>>>(qp, kp, vtb, mb, ap, pO, pL);
  combine<<<dim3(8, NHEADS, BB), 256, 0, stream>>>(pO, pL, ap);

  gemm_as<1><<<dim3(DD / 128, M / 128, 1), 256, 0, stream>>>(
      ap, Wot, bo, d_out, M, DD, DD, DD, 0, 1.0f);
}